// Round 5
// baseline (174.177 us; speedup 1.0000x reference)
//
#include <hip/hip_runtime.h>

typedef unsigned long long u64;
typedef short short8 __attribute__((ext_vector_type(8)));
typedef float f32x4 __attribute__((ext_vector_type(4)));

#define N_PTS   4096
#define B_SZ    4
#define N_PER_B 1024
#define L_TOK   16
#define FV      256
#define FL      768
#define FDIM    128
#define KNN     16
#define RH      64   // rel_encoder hidden

__device__ __forceinline__ short f2bf(float f) {
    unsigned int x = __float_as_uint(f);
    unsigned int r = (x + 0x7fffu + ((x >> 16) & 1u)) >> 16;
    return (short)r;
}
__device__ __forceinline__ void fma4(float4& a, float s, const float4 w) {
    a.x += s * w.x; a.y += s * w.y; a.z += s * w.z; a.w += s * w.w;
}

// =====================================================================
// A: knn (1024 blocks) + lang1 (64 blocks) + Wr2->bf16 transpose (1 block)
// =====================================================================
__global__ __launch_bounds__(256) void kA_kernel(const float* __restrict__ xyz,
                                                 const float* __restrict__ lf,
                                                 const float* __restrict__ Wl1,
                                                 const float* __restrict__ bl1,
                                                 const float* __restrict__ Wr2,
                                                 int* __restrict__ knn,
                                                 float* __restrict__ hl,
                                                 short* __restrict__ wr2t) {
    __shared__ float smem[1024];
    int b = blockIdx.x, t = threadIdx.x;

    if (b < 1024) {
        // ---------------- kNN: one wave per query ----------------
        int lane = t & 63;
        int q = b * 4 + (t >> 6);
        int base = (q >> 10) << 10;
        float qx = xyz[q * 3 + 0];
        float qy = xyz[q * 3 + 1];
        float qz = xyz[q * 3 + 2];
        u64 keys[16];
#pragma unroll
        for (int m = 0; m < 16; m++) {
            int j = base + lane + (m << 6);
            float dx = qx - xyz[j * 3 + 0];
            float dy = qy - xyz[j * 3 + 1];
            float dz = qz - xyz[j * 3 + 2];
            // match reference rounding: no fma contraction, (x+y) then +z
            float d2 = __fadd_rn(__fadd_rn(__fmul_rn(dx, dx), __fmul_rn(dy, dy)),
                                 __fmul_rn(dz, dz));
            keys[m] = (((u64)__float_as_uint(d2)) << 32) | (unsigned int)j;
        }
        for (int r = 0; r < KNN; r++) {
            u64 lmin = keys[0];
#pragma unroll
            for (int m = 1; m < 16; m++) lmin = (keys[m] < lmin) ? keys[m] : lmin;
            u64 g = lmin;
#pragma unroll
            for (int off = 32; off > 0; off >>= 1) {
                u64 o = __shfl_xor(g, off, 64);
                g = (o < g) ? o : g;
            }
#pragma unroll
            for (int m = 0; m < 16; m++)
                if (keys[m] == g) keys[m] = ~0ULL;
            if (lane == 0) knn[q * KNN + r] = (int)(g & 0xffffffffu);
        }
    } else if (b < 1088) {
        // ---------------- lang stage 1: hl = lang_row @ Wl1 + bl1 ------
        int r = b - 1024;
        float* lrow = smem;          // [768]
        float* part = smem + 768;    // [2][128]
        for (int k = t; k < FL; k += 256) lrow[k] = lf[r * FL + k];
        __syncthreads();
        int c = t & 127, kh = t >> 7;
        float acc = (kh == 0) ? bl1[c] : 0.f;
        int k0 = kh * 384;
        for (int k = k0; k < k0 + 384; k++) acc += lrow[k] * Wl1[k * FDIM + c];
        part[kh * FDIM + c] = acc;
        __syncthreads();
        if (kh == 0) hl[r * FDIM + c] = part[c] + part[FDIM + c];
    } else {
        // ---------------- Wr2 [64][128] -> wr2t bf16 [128][64] ----------
        for (int p = t; p < RH * FDIM; p += 256) {
            int c = p >> 6, k = p & 63;
            wr2t[c * RH + k] = f2bf(Wr2[k * FDIM + c]);
        }
    }
}

// =====================================================================
// B: lang stage 2 — BN (batch stats) + ReLU + GEMM2. 16 blocks × 4 rows.
// Also emits langT bf16 [B][128c][16l] for edge's MFMA B-fragments.
// =====================================================================
__global__ __launch_bounds__(128) void lang2_kernel(const float* __restrict__ hl,
                                                    const float* __restrict__ bn_g,
                                                    const float* __restrict__ bn_b,
                                                    const float* __restrict__ Wl2,
                                                    const float* __restrict__ bl2,
                                                    float* __restrict__ lang,
                                                    short* __restrict__ langT) {
    __shared__ float rl4[4][FDIM];
    int t = threadIdx.x;
    int r0 = blockIdx.x * 4;
    float s = 0.f, s2 = 0.f;
    for (int r = 0; r < 64; r++) {
        float v = hl[r * FDIM + t];
        s += v; s2 += v * v;
    }
    float mu = s * (1.f / 64.f);
    float var = s2 * (1.f / 64.f) - mu * mu;
    float rs = rsqrtf(var + 1e-5f);
    float g = bn_g[t], bb = bn_b[t];
#pragma unroll
    for (int p = 0; p < 4; p++)
        rl4[p][t] = fmaxf((hl[(r0 + p) * FDIM + t] - mu) * rs * g + bb, 0.f);
    __syncthreads();
    float bv = bl2[t];
    float a[4] = {bv, bv, bv, bv};
    for (int k = 0; k < FDIM; k++) {
        float w = Wl2[k * FDIM + t];
        a[0] += rl4[0][k] * w;
        a[1] += rl4[1][k] * w;
        a[2] += rl4[2][k] * w;
        a[3] += rl4[3][k] * w;
    }
#pragma unroll
    for (int p = 0; p < 4; p++) {
        int r = r0 + p;
        lang[r * FDIM + t] = a[p];
        langT[((r >> 4) * FDIM + t) * L_TOK + (r & 15)] = f2bf(a[p]);
    }
}

// =====================================================================
// C: feat encoder + atten, 16 points/block, 256 blocks.
// Thread owns 4 cols (colgroup=t&31) x 2 points (pslot=t>>5).
// W1/W2 read as float4 (16 FMA per global load); LN via width-32 shuffles.
// =====================================================================
__global__ __launch_bounds__(256) void feat_kernel(const float* __restrict__ features,
                                                   const float* __restrict__ W1,
                                                   const float* __restrict__ b1,
                                                   const float* __restrict__ ln_g,
                                                   const float* __restrict__ ln_b,
                                                   const float* __restrict__ W2,
                                                   const float* __restrict__ b2,
                                                   const float* __restrict__ lang,
                                                   float* __restrict__ feats,
                                                   float* __restrict__ atten) {
    __shared__ float fin[16 * FV];     // 16 KB
    __shared__ float rbuf[16 * FDIM];  // 8 KB
    __shared__ float fbuf[16 * FDIM];  // 8 KB
    int t = threadIdx.x;
    int i0 = blockIdx.x * 16;
    // stage 16 input rows (float4-coalesced)
    {
        const float4* src = (const float4*)(features + i0 * FV);
        float4* dst = (float4*)fin;
#pragma unroll
        for (int v = 0; v < 4; v++) dst[t + 256 * v] = src[t + 256 * v];
    }
    __syncthreads();
    int cg = t & 31, ps = t >> 5;
    int c0 = cg * 4;
    int p0 = ps * 2, p1 = p0 + 1;

    // ---- GEMM1: h = fin @ W1 + b1 ----
    float4 bv = *(const float4*)(b1 + c0);
    float4 a0 = bv, a1 = bv;
    for (int k4 = 0; k4 < FV / 4; k4++) {
        float4 f0 = *(const float4*)&fin[p0 * FV + k4 * 4];
        float4 f1 = *(const float4*)&fin[p1 * FV + k4 * 4];
        const float* wp = W1 + (k4 * 4) * FDIM + c0;
        float4 w;
        w = *(const float4*)(wp);            fma4(a0, f0.x, w); fma4(a1, f1.x, w);
        w = *(const float4*)(wp + FDIM);     fma4(a0, f0.y, w); fma4(a1, f1.y, w);
        w = *(const float4*)(wp + 2 * FDIM); fma4(a0, f0.z, w); fma4(a1, f1.z, w);
        w = *(const float4*)(wp + 3 * FDIM); fma4(a0, f0.w, w); fma4(a1, f1.w, w);
    }
    // ---- LayerNorm over 128 cols (32 lanes of this pslot group) ----
    float s0 = a0.x + a0.y + a0.z + a0.w;
    float q0 = a0.x * a0.x + a0.y * a0.y + a0.z * a0.z + a0.w * a0.w;
    float s1 = a1.x + a1.y + a1.z + a1.w;
    float q1 = a1.x * a1.x + a1.y * a1.y + a1.z * a1.z + a1.w * a1.w;
#pragma unroll
    for (int off = 1; off < 32; off <<= 1) {
        s0 += __shfl_xor(s0, off, 32);
        q0 += __shfl_xor(q0, off, 32);
        s1 += __shfl_xor(s1, off, 32);
        q1 += __shfl_xor(q1, off, 32);
    }
    float mu0 = s0 * (1.f / 128.f), var0 = q0 * (1.f / 128.f) - mu0 * mu0;
    float mu1 = s1 * (1.f / 128.f), var1 = q1 * (1.f / 128.f) - mu1 * mu1;
    float rs0 = rsqrtf(var0 + 1e-5f), rs1 = rsqrtf(var1 + 1e-5f);
    float4 g4 = *(const float4*)(ln_g + c0);
    float4 lb4 = *(const float4*)(ln_b + c0);
    float4 r0v, r1v;
    r0v.x = fmaxf((a0.x - mu0) * rs0 * g4.x + lb4.x, 0.f);
    r0v.y = fmaxf((a0.y - mu0) * rs0 * g4.y + lb4.y, 0.f);
    r0v.z = fmaxf((a0.z - mu0) * rs0 * g4.z + lb4.z, 0.f);
    r0v.w = fmaxf((a0.w - mu0) * rs0 * g4.w + lb4.w, 0.f);
    r1v.x = fmaxf((a1.x - mu1) * rs1 * g4.x + lb4.x, 0.f);
    r1v.y = fmaxf((a1.y - mu1) * rs1 * g4.y + lb4.y, 0.f);
    r1v.z = fmaxf((a1.z - mu1) * rs1 * g4.z + lb4.z, 0.f);
    r1v.w = fmaxf((a1.w - mu1) * rs1 * g4.w + lb4.w, 0.f);
    *(float4*)&rbuf[p0 * FDIM + c0] = r0v;
    *(float4*)&rbuf[p1 * FDIM + c0] = r1v;
    __syncthreads();

    // ---- GEMM2: f = relu_h @ W2 + b2 ----
    float4 bv2 = *(const float4*)(b2 + c0);
    float4 o0 = bv2, o1 = bv2;
    for (int k4 = 0; k4 < FDIM / 4; k4++) {
        float4 f0 = *(const float4*)&rbuf[p0 * FDIM + k4 * 4];
        float4 f1 = *(const float4*)&rbuf[p1 * FDIM + k4 * 4];
        const float* wp = W2 + (k4 * 4) * FDIM + c0;
        float4 w;
        w = *(const float4*)(wp);            fma4(o0, f0.x, w); fma4(o1, f1.x, w);
        w = *(const float4*)(wp + FDIM);     fma4(o0, f0.y, w); fma4(o1, f1.y, w);
        w = *(const float4*)(wp + 2 * FDIM); fma4(o0, f0.z, w); fma4(o1, f1.z, w);
        w = *(const float4*)(wp + 3 * FDIM); fma4(o0, f0.w, w); fma4(o1, f1.w, w);
    }
    *(float4*)(feats + (i0 + p0) * FDIM + c0) = o0;
    *(float4*)(feats + (i0 + p1) * FDIM + c0) = o1;
    *(float4*)&fbuf[p0 * FDIM + c0] = o0;
    *(float4*)&fbuf[p1 * FDIM + c0] = o1;
    __syncthreads();

    // ---- atten[i, l] = feats_i . lang[bi, l] : one (p,l) per thread ----
    int p = t >> 4, l = t & 15;
    int bi = i0 >> 10;
    const float4* lr = (const float4*)(lang + (bi * L_TOK + l) * FDIM);
    const float4* fr = (const float4*)&fbuf[p * FDIM];
    float acc = 0.f;
#pragma unroll
    for (int k = 0; k < FDIM / 4; k++) {
        float4 x = lr[k], y = fr[k];
        acc += x.x * y.x + x.y * y.y + x.z * y.z + x.w * y.w;
    }
    atten[(i0 + p) * L_TOK + l] = acc;
}

// =====================================================================
// D: edge kernel — one query per wave, zero LDS/barriers.
// Softmax via 16-lane shuffles; ew/ctx via bf16 MFMA 16x16x32 with
// preconverted bf16 B-fragments (wr2t, langT) loaded as short8.
// =====================================================================
__global__ __launch_bounds__(256) void edge_kernel(const float* __restrict__ xyz,
                                                   const float* __restrict__ mask,
                                                   const float* __restrict__ Wr1,
                                                   const float* __restrict__ br1,
                                                   const short* __restrict__ wr2t,
                                                   const float* __restrict__ br2,
                                                   const int* __restrict__ knn,
                                                   const short* __restrict__ langT,
                                                   const float* __restrict__ feats,
                                                   const float* __restrict__ atten,
                                                   float* __restrict__ out) {
    int lane = threadIdx.x & 63;
    int wid  = threadIdx.x >> 6;
    int i    = blockIdx.x * 4 + wid;          // query
    int bi   = i >> 10;
    int quad = lane >> 4;
    int e16  = lane & 15;

    int idxe = knn[i * KNN + e16];

    // ---- gather logits: lane holds l = quad*8 + j (quads 0,1 real) ----
    float sat[8];
    if (quad < 2) {
        const float4* ap = (const float4*)(atten + idxe * L_TOK + quad * 8);
        float4 a0 = ap[0], a1 = ap[1];
        sat[0] = a0.x; sat[1] = a0.y; sat[2] = a0.z; sat[3] = a0.w;
        sat[4] = a1.x; sat[5] = a1.y; sat[6] = a1.z; sat[7] = a1.w;
    } else {
#pragma unroll
        for (int j = 0; j < 8; j++) sat[j] = 0.f;
    }

    // ---- segment softmax over e (16-lane shuffle groups) ----
    float mx[8];
#pragma unroll
    for (int j = 0; j < 8; j++) mx[j] = sat[j];
#pragma unroll
    for (int off = 1; off < 16; off <<= 1) {
#pragma unroll
        for (int j = 0; j < 8; j++) mx[j] = fmaxf(mx[j], __shfl_xor(mx[j], off, 16));
    }
    float ex[8], sm[8];
#pragma unroll
    for (int j = 0; j < 8; j++) { ex[j] = __expf(sat[j] - mx[j]); sm[j] = ex[j]; }
#pragma unroll
    for (int off = 1; off < 16; off <<= 1) {
#pragma unroll
        for (int j = 0; j < 8; j++) sm[j] += __shfl_xor(sm[j], off, 16);
    }
    float st[8];
    if (quad < 2) {
        const float4* mp = (const float4*)(mask + i * L_TOK + quad * 8);
        float4 m0 = mp[0], m1 = mp[1];
        float mv[8] = {m0.x, m0.y, m0.z, m0.w, m1.x, m1.y, m1.z, m1.w};
#pragma unroll
        for (int j = 0; j < 8; j++) st[j] = ex[j] * (mv[j] / sm[j]);
    } else {
#pragma unroll
        for (int j = 0; j < 8; j++) st[j] = 0.f;
    }
    float s = st[0] + st[1] + st[2] + st[3] + st[4] + st[5] + st[6] + st[7];
    s += __shfl_xor(s, 16, 64);
    s += __shfl_xor(s, 32, 64);
    float inv2 = 1.f / (s + 1e-7f);
    short8 sattA;
#pragma unroll
    for (int j = 0; j < 8; j++) sattA[j] = f2bf(st[j] * inv2);

    // ---- rel_encoder hidden: hid[e=lane&15][k = s*32+quad*8+j] ----
    float xi0 = xyz[i * 3 + 0], xi1 = xyz[i * 3 + 1], xi2 = xyz[i * 3 + 2];
    float xj0 = xyz[idxe * 3 + 0], xj1 = xyz[idxe * 3 + 1], xj2 = xyz[idxe * 3 + 2];
    float d0 = xi0 - xj0, d1 = xi1 - xj1, d2v = xi2 - xj2;
    float nr = sqrtf(d0 * d0 + d1 * d1 + d2v * d2v + 1e-12f);
    float ein[10] = {xi0, xi1, xi2, xj0, xj1, xj2, d0, d1, d2v, nr};
    short8 hidA[2];
#pragma unroll
    for (int sstep = 0; sstep < 2; sstep++) {
        int k0 = sstep * 32 + quad * 8;
        float h[8];
        const float4* bp = (const float4*)(br1 + k0);
        float4 b0 = bp[0], b1v = bp[1];
        h[0] = b0.x; h[1] = b0.y; h[2] = b0.z; h[3] = b0.w;
        h[4] = b1v.x; h[5] = b1v.y; h[6] = b1v.z; h[7] = b1v.w;
#pragma unroll
        for (int m = 0; m < 10; m++) {
            const float4* wp = (const float4*)(Wr1 + m * RH + k0);
            float4 w0 = wp[0], w1 = wp[1];
            float em = ein[m];
            h[0] += em * w0.x; h[1] += em * w0.y; h[2] += em * w0.z; h[3] += em * w0.w;
            h[4] += em * w1.x; h[5] += em * w1.y; h[6] += em * w1.z; h[7] += em * w1.w;
        }
#pragma unroll
        for (int j = 0; j < 8; j++) hidA[sstep][j] = f2bf(fmaxf(h[j], 0.f));
    }

    int idxr[4];
#pragma unroll
    for (int r = 0; r < 4; r++) idxr[r] = knn[i * KNN + quad * 4 + r];

    // ---- per c-tile: ew MFMA (2 steps) + ctx MFMA (1 padded step) ----
#pragma unroll 2
    for (int tile = 0; tile < 8; tile++) {
        int cc = tile * 16 + e16;
        const short8* w2p = (const short8*)(wr2t + cc * RH);
        f32x4 accew = {0.f, 0.f, 0.f, 0.f};
        accew = __builtin_amdgcn_mfma_f32_16x16x32_bf16(hidA[0], w2p[quad],     accew, 0, 0, 0);
        accew = __builtin_amdgcn_mfma_f32_16x16x32_bf16(hidA[1], w2p[4 + quad], accew, 0, 0, 0);
        short8 lsB;
        if (quad < 2) {
            lsB = ((const short8*)(langT + (bi * FDIM + cc) * L_TOK))[quad];
        } else {
#pragma unroll
            for (int j = 0; j < 8; j++) lsB[j] = 0;
        }
        f32x4 accctx = {0.f, 0.f, 0.f, 0.f};
        accctx = __builtin_amdgcn_mfma_f32_16x16x32_bf16(sattA, lsB, accctx, 0, 0, 0);

        float br2c = br2[cc];
        float msum = 0.f;
#pragma unroll
        for (int r = 0; r < 4; r++) {
            float fj = feats[idxr[r] * FDIM + cc];
            msum += fj * accctx[r] * (accew[r] + br2c);
        }
        msum += __shfl_xor(msum, 16, 64);
        msum += __shfl_xor(msum, 32, 64);
        if (lane < 16)
            out[i * FDIM + cc] = feats[i * FDIM + cc] + msum;
    }
}

extern "C" void kernel_launch(void* const* d_in, const int* in_sizes, int n_in,
                              void* d_out, int out_size, void* d_ws, size_t ws_size,
                              hipStream_t stream) {
    const float* xyz   = (const float*)d_in[0];
    // d_in[1] = batch_index (int32) — layout-implied (i>>10), unused
    const float* features = (const float*)d_in[2];
    const float* lang_f   = (const float*)d_in[3];
    const float* mask     = (const float*)d_in[4];
    const float* W1   = (const float*)d_in[5];
    const float* b1   = (const float*)d_in[6];
    const float* ln_g = (const float*)d_in[7];
    const float* ln_b = (const float*)d_in[8];
    const float* W2   = (const float*)d_in[9];
    const float* b2   = (const float*)d_in[10];
    const float* Wl1  = (const float*)d_in[11];
    const float* bl1  = (const float*)d_in[12];
    const float* bn_g = (const float*)d_in[13];
    const float* bn_b = (const float*)d_in[14];
    const float* Wl2  = (const float*)d_in[15];
    const float* bl2  = (const float*)d_in[16];
    const float* Wr1  = (const float*)d_in[17];
    const float* br1  = (const float*)d_in[18];
    const float* Wr2  = (const float*)d_in[19];
    const float* br2  = (const float*)d_in[20];

    float* ws_feats = (float*)d_ws;                       // N*F
    float* ws_atten = ws_feats + N_PTS * FDIM;            // N*L
    float* ws_lang  = ws_atten + N_PTS * L_TOK;           // B*L*F
    float* ws_hl    = ws_lang + B_SZ * L_TOK * FDIM;      // 64*F
    int*   ws_knn   = (int*)(ws_hl + 64 * FDIM);          // N*K ints
    short* ws_wr2t  = (short*)(ws_knn + N_PTS * KNN);     // 128*64 bf16
    short* ws_langT = ws_wr2t + FDIM * RH;                // B*128*16 bf16

    kA_kernel<<<1089, 256, 0, stream>>>(xyz, lang_f, Wl1, bl1, Wr2,
                                        ws_knn, ws_hl, ws_wr2t);
    lang2_kernel<<<16, 128, 0, stream>>>(ws_hl, bn_g, bn_b, Wl2, bl2,
                                         ws_lang, ws_langT);
    feat_kernel<<<N_PTS / 16, 256, 0, stream>>>(features, W1, b1, ln_g, ln_b, W2, b2,
                                                ws_lang, ws_feats, ws_atten);
    edge_kernel<<<N_PTS / 4, 256, 0, stream>>>(xyz, mask, Wr1, br1, ws_wr2t, br2,
                                               ws_knn, ws_langT, ws_feats, ws_atten,
                                               (float*)d_out);
}

// Round 6
// 174.131 us; speedup vs baseline: 1.0003x; 1.0003x over previous
//
#include <hip/hip_runtime.h>

typedef unsigned long long u64;
typedef short short8 __attribute__((ext_vector_type(8)));
typedef short short4v __attribute__((ext_vector_type(4)));
typedef float f32x4 __attribute__((ext_vector_type(4)));

#define N_PTS   4096
#define B_SZ    4
#define N_PER_B 1024
#define L_TOK   16
#define FV      256
#define FL      768
#define FDIM    128
#define KNN     16
#define RH      64   // rel_encoder hidden

#define FINS 264   // fin LDS row stride (shorts), 528B = 16B-aligned
#define RBS  136   // rbuf LDS row stride (shorts), 272B
#define FBS  132   // fbuf LDS row stride (floats), 528B

__device__ __forceinline__ short f2bf(float f) {
    unsigned int x = __float_as_uint(f);
    unsigned int r = (x + 0x7fffu + ((x >> 16) & 1u)) >> 16;
    return (short)r;
}
__device__ __forceinline__ float bf2f(short s) {
    return __uint_as_float(((unsigned int)(unsigned short)s) << 16);
}

// =====================================================================
// A: knn (1024) + lang1 (64) + weight->bf16 hi/lo transposes (4 blocks)
// =====================================================================
__global__ __launch_bounds__(256) void kA_kernel(const float* __restrict__ xyz,
                                                 const float* __restrict__ lf,
                                                 const float* __restrict__ Wl1,
                                                 const float* __restrict__ bl1,
                                                 const float* __restrict__ Wr2,
                                                 const float* __restrict__ W1,
                                                 const float* __restrict__ W2,
                                                 int* __restrict__ knn,
                                                 float* __restrict__ hl,
                                                 short* __restrict__ wr2t,
                                                 short* __restrict__ w1t_hi,
                                                 short* __restrict__ w1t_lo,
                                                 short* __restrict__ w2t_hi,
                                                 short* __restrict__ w2t_lo) {
    __shared__ float smem[1024];
    int b = blockIdx.x, t = threadIdx.x;

    if (b < 1024) {
        // ---------------- kNN: one wave per query ----------------
        int lane = t & 63;
        int q = b * 4 + (t >> 6);
        int base = (q >> 10) << 10;
        float qx = xyz[q * 3 + 0];
        float qy = xyz[q * 3 + 1];
        float qz = xyz[q * 3 + 2];
        u64 keys[16];
#pragma unroll
        for (int m = 0; m < 16; m++) {
            int j = base + lane + (m << 6);
            float dx = qx - xyz[j * 3 + 0];
            float dy = qy - xyz[j * 3 + 1];
            float dz = qz - xyz[j * 3 + 2];
            // match reference rounding: no fma contraction, (x+y) then +z
            float d2 = __fadd_rn(__fadd_rn(__fmul_rn(dx, dx), __fmul_rn(dy, dy)),
                                 __fmul_rn(dz, dz));
            keys[m] = (((u64)__float_as_uint(d2)) << 32) | (unsigned int)j;
        }
        for (int r = 0; r < KNN; r++) {
            u64 lmin = keys[0];
#pragma unroll
            for (int m = 1; m < 16; m++) lmin = (keys[m] < lmin) ? keys[m] : lmin;
            u64 g = lmin;
#pragma unroll
            for (int off = 32; off > 0; off >>= 1) {
                u64 o = __shfl_xor(g, off, 64);
                g = (o < g) ? o : g;
            }
#pragma unroll
            for (int m = 0; m < 16; m++)
                if (keys[m] == g) keys[m] = ~0ULL;
            if (lane == 0) knn[q * KNN + r] = (int)(g & 0xffffffffu);
        }
    } else if (b < 1088) {
        // ---------------- lang stage 1: hl = lang_row @ Wl1 + bl1 ------
        int r = b - 1024;
        float* lrow = smem;          // [768]
        float* part = smem + 768;    // [2][128]
        for (int k = t; k < FL; k += 256) lrow[k] = lf[r * FL + k];
        __syncthreads();
        int c = t & 127, kh = t >> 7;
        float acc = (kh == 0) ? bl1[c] : 0.f;
        int k0 = kh * 384;
#pragma unroll 8
        for (int k = k0; k < k0 + 384; k++) acc += lrow[k] * Wl1[k * FDIM + c];
        part[kh * FDIM + c] = acc;
        __syncthreads();
        if (kh == 0) hl[r * FDIM + c] = part[c] + part[FDIM + c];
    } else if (b == 1088) {
        // Wr2 [64][128] -> wr2t bf16 [128][64]
        for (int p = t; p < RH * FDIM; p += 256) {
            int c = p >> 6, k = p & 63;
            wr2t[c * RH + k] = f2bf(Wr2[k * FDIM + c]);
        }
    } else if (b == 1089) {
        // W2 [128][128] -> w2t hi/lo [128c][128k]
        for (int p = t; p < FDIM * FDIM; p += 256) {
            int k = p >> 7, c = p & 127;
            float v = W2[p];
            short h = f2bf(v);
            w2t_hi[c * FDIM + k] = h;
            w2t_lo[c * FDIM + k] = f2bf(v - bf2f(h));
        }
    } else {
        // W1 [256][128] -> w1t hi/lo [128c][256k]; two blocks, k-halves
        int kbase = (b - 1090) * 128;
        for (int p = t; p < 128 * FDIM; p += 256) {
            int k = kbase + (p >> 7), c = p & 127;
            float v = W1[k * FDIM + c];
            short h = f2bf(v);
            w1t_hi[c * FV + k] = h;
            w1t_lo[c * FV + k] = f2bf(v - bf2f(h));
        }
    }
}

// =====================================================================
// B: lang stage 2 — BN (batch stats) + ReLU + GEMM2. 16 blocks × 4 rows.
// Emits lang fp32 and langT bf16 [B][128c][16l].
// =====================================================================
__global__ __launch_bounds__(128) void lang2_kernel(const float* __restrict__ hl,
                                                    const float* __restrict__ bn_g,
                                                    const float* __restrict__ bn_b,
                                                    const float* __restrict__ Wl2,
                                                    const float* __restrict__ bl2,
                                                    float* __restrict__ lang,
                                                    short* __restrict__ langT) {
    __shared__ float rl4[4][FDIM];
    int t = threadIdx.x;
    int r0 = blockIdx.x * 4;
    float s = 0.f, s2 = 0.f;
#pragma unroll 8
    for (int r = 0; r < 64; r++) {
        float v = hl[r * FDIM + t];
        s += v; s2 += v * v;
    }
    float mu = s * (1.f / 64.f);
    float var = s2 * (1.f / 64.f) - mu * mu;
    float rs = rsqrtf(var + 1e-5f);
    float g = bn_g[t], bb = bn_b[t];
#pragma unroll
    for (int p = 0; p < 4; p++)
        rl4[p][t] = fmaxf((hl[(r0 + p) * FDIM + t] - mu) * rs * g + bb, 0.f);
    __syncthreads();
    float bv = bl2[t];
    float a[4] = {bv, bv, bv, bv};
#pragma unroll 8
    for (int k = 0; k < FDIM; k++) {
        float w = Wl2[k * FDIM + t];
        a[0] += rl4[0][k] * w;
        a[1] += rl4[1][k] * w;
        a[2] += rl4[2][k] * w;
        a[3] += rl4[3][k] * w;
    }
#pragma unroll
    for (int p = 0; p < 4; p++) {
        int r = r0 + p;
        lang[r * FDIM + t] = a[p];
        langT[((r >> 4) * FDIM + t) * L_TOK + (r & 15)] = f2bf(a[p]);
    }
}

// =====================================================================
// C: feat encoder via bf16-split MFMA (3-mult, fp32-faithful) + atten.
// 256 blocks × 16 points; wave w owns cols [32w,32w+32) (2 n-tiles).
// =====================================================================
__global__ __launch_bounds__(256) void feat_kernel(const float* __restrict__ features,
                                                   const float* __restrict__ b1,
                                                   const float* __restrict__ ln_g,
                                                   const float* __restrict__ ln_b,
                                                   const float* __restrict__ b2,
                                                   const short* __restrict__ w1t_hi,
                                                   const short* __restrict__ w1t_lo,
                                                   const short* __restrict__ w2t_hi,
                                                   const short* __restrict__ w2t_lo,
                                                   const float* __restrict__ lang,
                                                   float* __restrict__ feats,
                                                   float* __restrict__ atten) {
    __shared__ short fin_hi[16 * FINS], fin_lo[16 * FINS];
    __shared__ short rb_hi[16 * RBS], rb_lo[16 * RBS];
    __shared__ float fbuf[16 * FBS];
    __shared__ float red_s[4 * 16], red_q[4 * 16];
    int t = threadIdx.x;
    int w = t >> 6, lane = t & 63, quad = lane >> 4, e16 = lane & 15;
    int i0 = blockIdx.x * 16;

    // ---- stage features -> bf16 hi/lo in LDS ----
    {
        const float4* src = (const float4*)(features + i0 * FV);
#pragma unroll
        for (int v = 0; v < 4; v++) {
            int flat = t + 256 * v;              // float4 index
            float4 x = src[flat];
            int p = flat >> 6, k = (flat & 63) * 4;
            short4v hi, lo;
            hi[0] = f2bf(x.x); lo[0] = f2bf(x.x - bf2f(hi[0]));
            hi[1] = f2bf(x.y); lo[1] = f2bf(x.y - bf2f(hi[1]));
            hi[2] = f2bf(x.z); lo[2] = f2bf(x.z - bf2f(hi[2]));
            hi[3] = f2bf(x.w); lo[3] = f2bf(x.w - bf2f(hi[3]));
            *(short4v*)&fin_hi[p * FINS + k] = hi;
            *(short4v*)&fin_lo[p * FINS + k] = lo;
        }
    }
    __syncthreads();

    int c0 = 32 * w + e16, c1 = c0 + 16;

    // ---- GEMM1: h = fin @ W1 (3-mult split) ----
    f32x4 acc0 = {0.f, 0.f, 0.f, 0.f}, acc1 = {0.f, 0.f, 0.f, 0.f};
#pragma unroll
    for (int s = 0; s < 8; s++) {
        int ko = s * 32 + quad * 8;
        short8 Ah = *(const short8*)&fin_hi[e16 * FINS + ko];
        short8 Al = *(const short8*)&fin_lo[e16 * FINS + ko];
        short8 B0h = *(const short8*)&w1t_hi[c0 * FV + ko];
        short8 B0l = *(const short8*)&w1t_lo[c0 * FV + ko];
        short8 B1h = *(const short8*)&w1t_hi[c1 * FV + ko];
        short8 B1l = *(const short8*)&w1t_lo[c1 * FV + ko];
        acc0 = __builtin_amdgcn_mfma_f32_16x16x32_bf16(Ah, B0h, acc0, 0, 0, 0);
        acc0 = __builtin_amdgcn_mfma_f32_16x16x32_bf16(Ah, B0l, acc0, 0, 0, 0);
        acc0 = __builtin_amdgcn_mfma_f32_16x16x32_bf16(Al, B0h, acc0, 0, 0, 0);
        acc1 = __builtin_amdgcn_mfma_f32_16x16x32_bf16(Ah, B1h, acc1, 0, 0, 0);
        acc1 = __builtin_amdgcn_mfma_f32_16x16x32_bf16(Ah, B1l, acc1, 0, 0, 0);
        acc1 = __builtin_amdgcn_mfma_f32_16x16x32_bf16(Al, B1h, acc1, 0, 0, 0);
    }
    float b1c0 = b1[c0], b1c1 = b1[c1];
    float h0[4], h1[4], sp[4], qp[4];
#pragma unroll
    for (int r = 0; r < 4; r++) {
        h0[r] = acc0[r] + b1c0;
        h1[r] = acc1[r] + b1c1;
        sp[r] = h0[r] + h1[r];
        qp[r] = h0[r] * h0[r] + h1[r] * h1[r];
    }
#pragma unroll
    for (int off = 1; off < 16; off <<= 1) {
#pragma unroll
        for (int r = 0; r < 4; r++) {
            sp[r] += __shfl_xor(sp[r], off, 16);
            qp[r] += __shfl_xor(qp[r], off, 16);
        }
    }
    if (e16 == 0) {
#pragma unroll
        for (int r = 0; r < 4; r++) {
            red_s[w * 16 + quad * 4 + r] = sp[r];
            red_q[w * 16 + quad * 4 + r] = qp[r];
        }
    }
    __syncthreads();
    float g0 = ln_g[c0], g1 = ln_g[c1], be0 = ln_b[c0], be1 = ln_b[c1];
#pragma unroll
    for (int r = 0; r < 4; r++) {
        int p = quad * 4 + r;
        float S = red_s[p] + red_s[16 + p] + red_s[32 + p] + red_s[48 + p];
        float Q = red_q[p] + red_q[16 + p] + red_q[32 + p] + red_q[48 + p];
        float mu = S * (1.f / 128.f);
        float var = Q * (1.f / 128.f) - mu * mu;
        float rs = rsqrtf(var + 1e-5f);
        float r0 = fmaxf((h0[r] - mu) * rs * g0 + be0, 0.f);
        float r1 = fmaxf((h1[r] - mu) * rs * g1 + be1, 0.f);
        short hh;
        hh = f2bf(r0); rb_hi[p * RBS + c0] = hh; rb_lo[p * RBS + c0] = f2bf(r0 - bf2f(hh));
        hh = f2bf(r1); rb_hi[p * RBS + c1] = hh; rb_lo[p * RBS + c1] = f2bf(r1 - bf2f(hh));
    }
    __syncthreads();

    // ---- GEMM2: f = relu_h @ W2 (3-mult split) ----
    f32x4 o0 = {0.f, 0.f, 0.f, 0.f}, o1 = {0.f, 0.f, 0.f, 0.f};
#pragma unroll
    for (int s = 0; s < 4; s++) {
        int ko = s * 32 + quad * 8;
        short8 Ah = *(const short8*)&rb_hi[e16 * RBS + ko];
        short8 Al = *(const short8*)&rb_lo[e16 * RBS + ko];
        short8 B0h = *(const short8*)&w2t_hi[c0 * FDIM + ko];
        short8 B0l = *(const short8*)&w2t_lo[c0 * FDIM + ko];
        short8 B1h = *(const short8*)&w2t_hi[c1 * FDIM + ko];
        short8 B1l = *(const short8*)&w2t_lo[c1 * FDIM + ko];
        o0 = __builtin_amdgcn_mfma_f32_16x16x32_bf16(Ah, B0h, o0, 0, 0, 0);
        o0 = __builtin_amdgcn_mfma_f32_16x16x32_bf16(Ah, B0l, o0, 0, 0, 0);
        o0 = __builtin_amdgcn_mfma_f32_16x16x32_bf16(Al, B0h, o0, 0, 0, 0);
        o1 = __builtin_amdgcn_mfma_f32_16x16x32_bf16(Ah, B1h, o1, 0, 0, 0);
        o1 = __builtin_amdgcn_mfma_f32_16x16x32_bf16(Ah, B1l, o1, 0, 0, 0);
        o1 = __builtin_amdgcn_mfma_f32_16x16x32_bf16(Al, B1h, o1, 0, 0, 0);
    }
    float b20 = b2[c0], b21 = b2[c1];
#pragma unroll
    for (int r = 0; r < 4; r++) {
        int p = quad * 4 + r;
        float f0 = o0[r] + b20, f1 = o1[r] + b21;
        feats[(i0 + p) * FDIM + c0] = f0;
        feats[(i0 + p) * FDIM + c1] = f1;
        fbuf[p * FBS + c0] = f0;
        fbuf[p * FBS + c1] = f1;
    }
    __syncthreads();

    // ---- atten[i,l] = feats_i . lang[bi,l] : one (p,l) per thread ----
    int pp = t >> 4, l = t & 15;
    int bi = i0 >> 10;
    const float4* lr = (const float4*)(lang + (bi * L_TOK + l) * FDIM);
    float acc = 0.f;
#pragma unroll
    for (int k = 0; k < FDIM / 4; k++) {
        float4 x = lr[k];
        float4 y = *(const float4*)&fbuf[pp * FBS + 4 * k];
        acc += x.x * y.x + x.y * y.y + x.z * y.z + x.w * y.w;
    }
    atten[(i0 + pp) * L_TOK + l] = acc;
}

// =====================================================================
// D: edge kernel — one query per wave, zero LDS/barriers.
// Softmax via 16-lane shuffles; ew/ctx via bf16 MFMA 16x16x32 with
// preconverted bf16 B-fragments (wr2t, langT) loaded as short8.
// =====================================================================
__global__ __launch_bounds__(256) void edge_kernel(const float* __restrict__ xyz,
                                                   const float* __restrict__ mask,
                                                   const float* __restrict__ Wr1,
                                                   const float* __restrict__ br1,
                                                   const short* __restrict__ wr2t,
                                                   const float* __restrict__ br2,
                                                   const int* __restrict__ knn,
                                                   const short* __restrict__ langT,
                                                   const float* __restrict__ feats,
                                                   const float* __restrict__ atten,
                                                   float* __restrict__ out) {
    int lane = threadIdx.x & 63;
    int wid  = threadIdx.x >> 6;
    int i    = blockIdx.x * 4 + wid;          // query
    int bi   = i >> 10;
    int quad = lane >> 4;
    int e16  = lane & 15;

    int idxe = knn[i * KNN + e16];

    // ---- gather logits: lane holds l = quad*8 + j (quads 0,1 real) ----
    float sat[8];
    if (quad < 2) {
        const float4* ap = (const float4*)(atten + idxe * L_TOK + quad * 8);
        float4 a0 = ap[0], a1 = ap[1];
        sat[0] = a0.x; sat[1] = a0.y; sat[2] = a0.z; sat[3] = a0.w;
        sat[4] = a1.x; sat[5] = a1.y; sat[6] = a1.z; sat[7] = a1.w;
    } else {
#pragma unroll
        for (int j = 0; j < 8; j++) sat[j] = 0.f;
    }

    // ---- segment softmax over e (16-lane shuffle groups) ----
    float mx[8];
#pragma unroll
    for (int j = 0; j < 8; j++) mx[j] = sat[j];
#pragma unroll
    for (int off = 1; off < 16; off <<= 1) {
#pragma unroll
        for (int j = 0; j < 8; j++) mx[j] = fmaxf(mx[j], __shfl_xor(mx[j], off, 16));
    }
    float ex[8], sm[8];
#pragma unroll
    for (int j = 0; j < 8; j++) { ex[j] = __expf(sat[j] - mx[j]); sm[j] = ex[j]; }
#pragma unroll
    for (int off = 1; off < 16; off <<= 1) {
#pragma unroll
        for (int j = 0; j < 8; j++) sm[j] += __shfl_xor(sm[j], off, 16);
    }
    float st[8];
    if (quad < 2) {
        const float4* mp = (const float4*)(mask + i * L_TOK + quad * 8);
        float4 m0 = mp[0], m1 = mp[1];
        float mv[8] = {m0.x, m0.y, m0.z, m0.w, m1.x, m1.y, m1.z, m1.w};
#pragma unroll
        for (int j = 0; j < 8; j++) st[j] = ex[j] * (mv[j] / sm[j]);
    } else {
#pragma unroll
        for (int j = 0; j < 8; j++) st[j] = 0.f;
    }
    float s = st[0] + st[1] + st[2] + st[3] + st[4] + st[5] + st[6] + st[7];
    s += __shfl_xor(s, 16, 64);
    s += __shfl_xor(s, 32, 64);
    float inv2 = 1.f / (s + 1e-7f);
    short8 sattA;
#pragma unroll
    for (int j = 0; j < 8; j++) sattA[j] = f2bf(st[j] * inv2);

    // ---- rel_encoder hidden: hid[e=lane&15][k = s*32+quad*8+j] ----
    float xi0 = xyz[i * 3 + 0], xi1 = xyz[i * 3 + 1], xi2 = xyz[i * 3 + 2];
    float xj0 = xyz[idxe * 3 + 0], xj1 = xyz[idxe * 3 + 1], xj2 = xyz[idxe * 3 + 2];
    float d0 = xi0 - xj0, d1 = xi1 - xj1, d2v = xi2 - xj2;
    float nr = sqrtf(d0 * d0 + d1 * d1 + d2v * d2v + 1e-12f);
    float ein[10] = {xi0, xi1, xi2, xj0, xj1, xj2, d0, d1, d2v, nr};
    short8 hidA[2];
#pragma unroll
    for (int sstep = 0; sstep < 2; sstep++) {
        int k0 = sstep * 32 + quad * 8;
        float h[8];
        const float4* bp = (const float4*)(br1 + k0);
        float4 b0 = bp[0], b1v = bp[1];
        h[0] = b0.x; h[1] = b0.y; h[2] = b0.z; h[3] = b0.w;
        h[4] = b1v.x; h[5] = b1v.y; h[6] = b1v.z; h[7] = b1v.w;
#pragma unroll
        for (int m = 0; m < 10; m++) {
            const float4* wp = (const float4*)(Wr1 + m * RH + k0);
            float4 w0 = wp[0], w1 = wp[1];
            float em = ein[m];
            h[0] += em * w0.x; h[1] += em * w0.y; h[2] += em * w0.z; h[3] += em * w0.w;
            h[4] += em * w1.x; h[5] += em * w1.y; h[6] += em * w1.z; h[7] += em * w1.w;
        }
#pragma unroll
        for (int j = 0; j < 8; j++) hidA[sstep][j] = f2bf(fmaxf(h[j], 0.f));
    }

    int idxr[4];
#pragma unroll
    for (int r = 0; r < 4; r++) idxr[r] = knn[i * KNN + quad * 4 + r];

    // ---- per c-tile: ew MFMA (2 steps) + ctx MFMA (1 padded step) ----
#pragma unroll 2
    for (int tile = 0; tile < 8; tile++) {
        int cc = tile * 16 + e16;
        const short8* w2p = (const short8*)(wr2t + cc * RH);
        f32x4 accew = {0.f, 0.f, 0.f, 0.f};
        accew = __builtin_amdgcn_mfma_f32_16x16x32_bf16(hidA[0], w2p[quad],     accew, 0, 0, 0);
        accew = __builtin_amdgcn_mfma_f32_16x16x32_bf16(hidA[1], w2p[4 + quad], accew, 0, 0, 0);
        short8 lsB;
        if (quad < 2) {
            lsB = ((const short8*)(langT + (bi * FDIM + cc) * L_TOK))[quad];
        } else {
#pragma unroll
            for (int j = 0; j < 8; j++) lsB[j] = 0;
        }
        f32x4 accctx = {0.f, 0.f, 0.f, 0.f};
        accctx = __builtin_amdgcn_mfma_f32_16x16x32_bf16(sattA, lsB, accctx, 0, 0, 0);

        float br2c = br2[cc];
        float msum = 0.f;
#pragma unroll
        for (int r = 0; r < 4; r++) {
            float fj = feats[idxr[r] * FDIM + cc];
            msum += fj * accctx[r] * (accew[r] + br2c);
        }
        msum += __shfl_xor(msum, 16, 64);
        msum += __shfl_xor(msum, 32, 64);
        if (lane < 16)
            out[i * FDIM + cc] = feats[i * FDIM + cc] + msum;
    }
}

extern "C" void kernel_launch(void* const* d_in, const int* in_sizes, int n_in,
                              void* d_out, int out_size, void* d_ws, size_t ws_size,
                              hipStream_t stream) {
    const float* xyz   = (const float*)d_in[0];
    // d_in[1] = batch_index (int32) — layout-implied (i>>10), unused
    const float* features = (const float*)d_in[2];
    const float* lang_f   = (const float*)d_in[3];
    const float* mask     = (const float*)d_in[4];
    const float* W1   = (const float*)d_in[5];
    const float* b1   = (const float*)d_in[6];
    const float* ln_g = (const float*)d_in[7];
    const float* ln_b = (const float*)d_in[8];
    const float* W2   = (const float*)d_in[9];
    const float* b2   = (const float*)d_in[10];
    const float* Wl1  = (const float*)d_in[11];
    const float* bl1  = (const float*)d_in[12];
    const float* bn_g = (const float*)d_in[13];
    const float* bn_b = (const float*)d_in[14];
    const float* Wl2  = (const float*)d_in[15];
    const float* bl2  = (const float*)d_in[16];
    const float* Wr1  = (const float*)d_in[17];
    const float* br1  = (const float*)d_in[18];
    const float* Wr2  = (const float*)d_in[19];
    const float* br2  = (const float*)d_in[20];

    float* ws_feats = (float*)d_ws;                       // N*F
    float* ws_atten = ws_feats + N_PTS * FDIM;            // N*L
    float* ws_lang  = ws_atten + N_PTS * L_TOK;           // B*L*F
    float* ws_hl    = ws_lang + B_SZ * L_TOK * FDIM;      // 64*F
    int*   ws_knn   = (int*)(ws_hl + 64 * FDIM);          // N*K ints
    short* ws_wr2t  = (short*)(ws_knn + N_PTS * KNN);     // 128*64 bf16
    short* ws_langT = ws_wr2t + FDIM * RH;                // B*128*16 bf16
    short* ws_w1t_hi = ws_langT + B_SZ * FDIM * L_TOK;    // 128*256
    short* ws_w1t_lo = ws_w1t_hi + FDIM * FV;             // 128*256
    short* ws_w2t_hi = ws_w1t_lo + FDIM * FV;             // 128*128
    short* ws_w2t_lo = ws_w2t_hi + FDIM * FDIM;           // 128*128

    kA_kernel<<<1092, 256, 0, stream>>>(xyz, lang_f, Wl1, bl1, Wr2, W1, W2,
                                        ws_knn, ws_hl, ws_wr2t,
                                        ws_w1t_hi, ws_w1t_lo, ws_w2t_hi, ws_w2t_lo);
    lang2_kernel<<<16, 128, 0, stream>>>(ws_hl, bn_g, bn_b, Wl2, bl2,
                                         ws_lang, ws_langT);
    feat_kernel<<<N_PTS / 16, 256, 0, stream>>>(features, b1, ln_g, ln_b, b2,
                                                ws_w1t_hi, ws_w1t_lo,
                                                ws_w2t_hi, ws_w2t_lo,
                                                ws_lang, ws_feats, ws_atten);
    edge_kernel<<<N_PTS / 4, 256, 0, stream>>>(xyz, mask, Wr1, br1, ws_wr2t, br2,
                                               ws_knn, ws_langT, ws_feats, ws_atten,
                                               (float*)d_out);
}

// Round 7
// 171.243 us; speedup vs baseline: 1.0171x; 1.0169x over previous
//
#include <hip/hip_runtime.h>

typedef unsigned long long u64;
typedef short short8 __attribute__((ext_vector_type(8)));
typedef short short4v __attribute__((ext_vector_type(4)));
typedef float f32x4 __attribute__((ext_vector_type(4)));

#define N_PTS   4096
#define B_SZ    4
#define N_PER_B 1024
#define L_TOK   16
#define FV      256
#define FL      768
#define FDIM    128
#define KNN     16
#define RH      64   // rel_encoder hidden

#define FINS 264   // fin LDS row stride (shorts), 528B = 16B-aligned
#define RBS  136   // rbuf LDS row stride (shorts), 272B
#define FBS  132   // fbuf LDS row stride (floats), 528B

__device__ __forceinline__ short f2bf(float f) {
    unsigned int x = __float_as_uint(f);
    unsigned int r = (x + 0x7fffu + ((x >> 16) & 1u)) >> 16;
    return (short)r;
}
__device__ __forceinline__ float bf2f(short s) {
    return __uint_as_float(((unsigned int)(unsigned short)s) << 16);
}
__device__ __forceinline__ int mbcnt64(u64 m) {
    return __builtin_amdgcn_mbcnt_hi((unsigned)(m >> 32),
                                     __builtin_amdgcn_mbcnt_lo((unsigned)m, 0));
}

// =====================================================================
// A: knn (1024) + lang1 (64) + weight->bf16 hi/lo transposes (4 blocks)
// kNN via radix-select on distance bits (no shuffle chains).
// =====================================================================
__global__ __launch_bounds__(256) void kA_kernel(const float* __restrict__ xyz,
                                                 const float* __restrict__ lf,
                                                 const float* __restrict__ Wl1,
                                                 const float* __restrict__ bl1,
                                                 const float* __restrict__ Wr2,
                                                 const float* __restrict__ W1,
                                                 const float* __restrict__ W2,
                                                 int* __restrict__ knn,
                                                 float* __restrict__ hl,
                                                 short* __restrict__ wr2t,
                                                 short* __restrict__ w1t_hi,
                                                 short* __restrict__ w1t_lo,
                                                 short* __restrict__ w2t_hi,
                                                 short* __restrict__ w2t_lo) {
    __shared__ float smem[1024];
    int b = blockIdx.x, t = threadIdx.x;

    if (b < 1024) {
        // ---------------- kNN: one wave per query, radix-select -------
        int lane = t & 63;
        int q = b * 4 + (t >> 6);
        int base = (q >> 10) << 10;
        float qx = xyz[q * 3 + 0];
        float qy = xyz[q * 3 + 1];
        float qz = xyz[q * 3 + 2];
        unsigned keys[16], xk[16];
#pragma unroll
        for (int m = 0; m < 16; m++) {
            int j = base + lane + (m << 6);
            float dx = qx - xyz[j * 3 + 0];
            float dy = qy - xyz[j * 3 + 1];
            float dz = qz - xyz[j * 3 + 2];
            // match reference rounding: no fma contraction, (x+y) then +z
            float d2 = __fadd_rn(__fadd_rn(__fmul_rn(dx, dx), __fmul_rn(dy, dy)),
                                 __fmul_rn(dz, dz));
            keys[m] = __float_as_uint(d2);
            xk[m] = keys[m];
        }
        // bit-plane descent: after the loop, `prefix` is the 16th-smallest
        // key value; `need` = how many ties at == prefix to take.
        unsigned prefix = 0;
        int need = 16;
#pragma unroll
        for (int bit = 30; bit >= 0; --bit) {
            unsigned lim = 1u << bit;
            int c = 0;
#pragma unroll
            for (int m = 0; m < 16; m++)
                c += __popcll(__ballot(xk[m] < lim));
            if (c < need) {
                need -= c;
                prefix |= lim;
#pragma unroll
                for (int m = 0; m < 16; m++) xk[m] ^= lim;
            }
        }
        // emit: all keys < prefix, plus `need` ties (== prefix) with
        // smallest index (matches top_k's stable tie-break). Order within
        // the query is irrelevant (segment ops are permutation-invariant).
        int pos = 0;
#pragma unroll
        for (int m = 0; m < 16; m++) {
            bool less = keys[m] < prefix;
            bool eqv  = (xk[m] == 0);
            u64 em = __ballot(eqv);
            bool take_eq = false;
            if (need > 0) {
                int ec = __popcll(em);
                if (ec <= need) {
                    take_eq = eqv;
                    need -= ec;
                } else {
                    take_eq = eqv && (mbcnt64(em) < need);
                    need = 0;
                }
            }
            bool sel = less || take_eq;
            u64 sm = __ballot(sel);
            if (sel) {
                int my = pos + mbcnt64(sm);
                knn[q * KNN + my] = base + lane + (m << 6);
            }
            pos += __popcll(sm);
        }
    } else if (b < 1088) {
        // ---------------- lang stage 1: hl = lang_row @ Wl1 + bl1 ------
        int r = b - 1024;
        float* lrow = smem;          // [768]
        float* part = smem + 768;    // [2][128]
        for (int k = t; k < FL; k += 256) lrow[k] = lf[r * FL + k];
        __syncthreads();
        int c = t & 127, kh = t >> 7;
        float acc = (kh == 0) ? bl1[c] : 0.f;
        int k0 = kh * 384;
#pragma unroll 8
        for (int k = k0; k < k0 + 384; k++) acc += lrow[k] * Wl1[k * FDIM + c];
        part[kh * FDIM + c] = acc;
        __syncthreads();
        if (kh == 0) hl[r * FDIM + c] = part[c] + part[FDIM + c];
    } else if (b == 1088) {
        // Wr2 [64][128] -> wr2t bf16 [128][64]
        for (int p = t; p < RH * FDIM; p += 256) {
            int c = p >> 6, k = p & 63;
            wr2t[c * RH + k] = f2bf(Wr2[k * FDIM + c]);
        }
    } else if (b == 1089) {
        // W2 [128][128] -> w2t hi/lo [128c][128k]
        for (int p = t; p < FDIM * FDIM; p += 256) {
            int k = p >> 7, c = p & 127;
            float v = W2[p];
            short h = f2bf(v);
            w2t_hi[c * FDIM + k] = h;
            w2t_lo[c * FDIM + k] = f2bf(v - bf2f(h));
        }
    } else {
        // W1 [256][128] -> w1t hi/lo [128c][256k]; two blocks, k-halves
        int kbase = (b - 1090) * 128;
        for (int p = t; p < 128 * FDIM; p += 256) {
            int k = kbase + (p >> 7), c = p & 127;
            float v = W1[k * FDIM + c];
            short h = f2bf(v);
            w1t_hi[c * FV + k] = h;
            w1t_lo[c * FV + k] = f2bf(v - bf2f(h));
        }
    }
}

// =====================================================================
// B: lang stage 2 — BN (batch stats) + ReLU + GEMM2. 16 blocks × 4 rows.
// Emits lang fp32 and langT bf16 [B][128c][16l].
// =====================================================================
__global__ __launch_bounds__(128) void lang2_kernel(const float* __restrict__ hl,
                                                    const float* __restrict__ bn_g,
                                                    const float* __restrict__ bn_b,
                                                    const float* __restrict__ Wl2,
                                                    const float* __restrict__ bl2,
                                                    float* __restrict__ lang,
                                                    short* __restrict__ langT) {
    __shared__ float rl4[4][FDIM];
    int t = threadIdx.x;
    int r0 = blockIdx.x * 4;
    float s = 0.f, s2 = 0.f;
#pragma unroll 8
    for (int r = 0; r < 64; r++) {
        float v = hl[r * FDIM + t];
        s += v; s2 += v * v;
    }
    float mu = s * (1.f / 64.f);
    float var = s2 * (1.f / 64.f) - mu * mu;
    float rs = rsqrtf(var + 1e-5f);
    float g = bn_g[t], bb = bn_b[t];
#pragma unroll
    for (int p = 0; p < 4; p++)
        rl4[p][t] = fmaxf((hl[(r0 + p) * FDIM + t] - mu) * rs * g + bb, 0.f);
    __syncthreads();
    float bv = bl2[t];
    float a[4] = {bv, bv, bv, bv};
#pragma unroll 8
    for (int k = 0; k < FDIM; k++) {
        float w = Wl2[k * FDIM + t];
        a[0] += rl4[0][k] * w;
        a[1] += rl4[1][k] * w;
        a[2] += rl4[2][k] * w;
        a[3] += rl4[3][k] * w;
    }
#pragma unroll
    for (int p = 0; p < 4; p++) {
        int r = r0 + p;
        lang[r * FDIM + t] = a[p];
        langT[((r >> 4) * FDIM + t) * L_TOK + (r & 15)] = f2bf(a[p]);
    }
}

// =====================================================================
// C: feat encoder via bf16-split MFMA (3-mult, fp32-faithful) + atten.
// 256 blocks × 16 points; wave w owns cols [32w,32w+32) (2 n-tiles).
// =====================================================================
__global__ __launch_bounds__(256) void feat_kernel(const float* __restrict__ features,
                                                   const float* __restrict__ b1,
                                                   const float* __restrict__ ln_g,
                                                   const float* __restrict__ ln_b,
                                                   const float* __restrict__ b2,
                                                   const short* __restrict__ w1t_hi,
                                                   const short* __restrict__ w1t_lo,
                                                   const short* __restrict__ w2t_hi,
                                                   const short* __restrict__ w2t_lo,
                                                   const float* __restrict__ lang,
                                                   float* __restrict__ feats,
                                                   float* __restrict__ atten) {
    __shared__ short fin_hi[16 * FINS], fin_lo[16 * FINS];
    __shared__ short rb_hi[16 * RBS], rb_lo[16 * RBS];
    __shared__ float fbuf[16 * FBS];
    __shared__ float red_s[4 * 16], red_q[4 * 16];
    int t = threadIdx.x;
    int w = t >> 6, lane = t & 63, quad = lane >> 4, e16 = lane & 15;
    int i0 = blockIdx.x * 16;

    // ---- stage features -> bf16 hi/lo in LDS ----
    {
        const float4* src = (const float4*)(features + i0 * FV);
#pragma unroll
        for (int v = 0; v < 4; v++) {
            int flat = t + 256 * v;              // float4 index
            float4 x = src[flat];
            int p = flat >> 6, k = (flat & 63) * 4;
            short4v hi, lo;
            hi[0] = f2bf(x.x); lo[0] = f2bf(x.x - bf2f(hi[0]));
            hi[1] = f2bf(x.y); lo[1] = f2bf(x.y - bf2f(hi[1]));
            hi[2] = f2bf(x.z); lo[2] = f2bf(x.z - bf2f(hi[2]));
            hi[3] = f2bf(x.w); lo[3] = f2bf(x.w - bf2f(hi[3]));
            *(short4v*)&fin_hi[p * FINS + k] = hi;
            *(short4v*)&fin_lo[p * FINS + k] = lo;
        }
    }
    __syncthreads();

    int c0 = 32 * w + e16, c1 = c0 + 16;

    // ---- GEMM1: h = fin @ W1 (3-mult split) ----
    f32x4 acc0 = {0.f, 0.f, 0.f, 0.f}, acc1 = {0.f, 0.f, 0.f, 0.f};
#pragma unroll
    for (int s = 0; s < 8; s++) {
        int ko = s * 32 + quad * 8;
        short8 Ah = *(const short8*)&fin_hi[e16 * FINS + ko];
        short8 Al = *(const short8*)&fin_lo[e16 * FINS + ko];
        short8 B0h = *(const short8*)&w1t_hi[c0 * FV + ko];
        short8 B0l = *(const short8*)&w1t_lo[c0 * FV + ko];
        short8 B1h = *(const short8*)&w1t_hi[c1 * FV + ko];
        short8 B1l = *(const short8*)&w1t_lo[c1 * FV + ko];
        acc0 = __builtin_amdgcn_mfma_f32_16x16x32_bf16(Ah, B0h, acc0, 0, 0, 0);
        acc0 = __builtin_amdgcn_mfma_f32_16x16x32_bf16(Ah, B0l, acc0, 0, 0, 0);
        acc0 = __builtin_amdgcn_mfma_f32_16x16x32_bf16(Al, B0h, acc0, 0, 0, 0);
        acc1 = __builtin_amdgcn_mfma_f32_16x16x32_bf16(Ah, B1h, acc1, 0, 0, 0);
        acc1 = __builtin_amdgcn_mfma_f32_16x16x32_bf16(Ah, B1l, acc1, 0, 0, 0);
        acc1 = __builtin_amdgcn_mfma_f32_16x16x32_bf16(Al, B1h, acc1, 0, 0, 0);
    }
    float b1c0 = b1[c0], b1c1 = b1[c1];
    float h0[4], h1[4], sp[4], qp[4];
#pragma unroll
    for (int r = 0; r < 4; r++) {
        h0[r] = acc0[r] + b1c0;
        h1[r] = acc1[r] + b1c1;
        sp[r] = h0[r] + h1[r];
        qp[r] = h0[r] * h0[r] + h1[r] * h1[r];
    }
#pragma unroll
    for (int off = 1; off < 16; off <<= 1) {
#pragma unroll
        for (int r = 0; r < 4; r++) {
            sp[r] += __shfl_xor(sp[r], off, 16);
            qp[r] += __shfl_xor(qp[r], off, 16);
        }
    }
    if (e16 == 0) {
#pragma unroll
        for (int r = 0; r < 4; r++) {
            red_s[w * 16 + quad * 4 + r] = sp[r];
            red_q[w * 16 + quad * 4 + r] = qp[r];
        }
    }
    __syncthreads();
    float g0 = ln_g[c0], g1 = ln_g[c1], be0 = ln_b[c0], be1 = ln_b[c1];
#pragma unroll
    for (int r = 0; r < 4; r++) {
        int p = quad * 4 + r;
        float S = red_s[p] + red_s[16 + p] + red_s[32 + p] + red_s[48 + p];
        float Q = red_q[p] + red_q[16 + p] + red_q[32 + p] + red_q[48 + p];
        float mu = S * (1.f / 128.f);
        float var = Q * (1.f / 128.f) - mu * mu;
        float rs = rsqrtf(var + 1e-5f);
        float r0 = fmaxf((h0[r] - mu) * rs * g0 + be0, 0.f);
        float r1 = fmaxf((h1[r] - mu) * rs * g1 + be1, 0.f);
        short hh;
        hh = f2bf(r0); rb_hi[p * RBS + c0] = hh; rb_lo[p * RBS + c0] = f2bf(r0 - bf2f(hh));
        hh = f2bf(r1); rb_hi[p * RBS + c1] = hh; rb_lo[p * RBS + c1] = f2bf(r1 - bf2f(hh));
    }
    __syncthreads();

    // ---- GEMM2: f = relu_h @ W2 (3-mult split) ----
    f32x4 o0 = {0.f, 0.f, 0.f, 0.f}, o1 = {0.f, 0.f, 0.f, 0.f};
#pragma unroll
    for (int s = 0; s < 4; s++) {
        int ko = s * 32 + quad * 8;
        short8 Ah = *(const short8*)&rb_hi[e16 * RBS + ko];
        short8 Al = *(const short8*)&rb_lo[e16 * RBS + ko];
        short8 B0h = *(const short8*)&w2t_hi[c0 * FDIM + ko];
        short8 B0l = *(const short8*)&w2t_lo[c0 * FDIM + ko];
        short8 B1h = *(const short8*)&w2t_hi[c1 * FDIM + ko];
        short8 B1l = *(const short8*)&w2t_lo[c1 * FDIM + ko];
        o0 = __builtin_amdgcn_mfma_f32_16x16x32_bf16(Ah, B0h, o0, 0, 0, 0);
        o0 = __builtin_amdgcn_mfma_f32_16x16x32_bf16(Ah, B0l, o0, 0, 0, 0);
        o0 = __builtin_amdgcn_mfma_f32_16x16x32_bf16(Al, B0h, o0, 0, 0, 0);
        o1 = __builtin_amdgcn_mfma_f32_16x16x32_bf16(Ah, B1h, o1, 0, 0, 0);
        o1 = __builtin_amdgcn_mfma_f32_16x16x32_bf16(Ah, B1l, o1, 0, 0, 0);
        o1 = __builtin_amdgcn_mfma_f32_16x16x32_bf16(Al, B1h, o1, 0, 0, 0);
    }
    float b20 = b2[c0], b21 = b2[c1];
#pragma unroll
    for (int r = 0; r < 4; r++) {
        int p = quad * 4 + r;
        float f0 = o0[r] + b20, f1 = o1[r] + b21;
        feats[(i0 + p) * FDIM + c0] = f0;
        feats[(i0 + p) * FDIM + c1] = f1;
        fbuf[p * FBS + c0] = f0;
        fbuf[p * FBS + c1] = f1;
    }
    __syncthreads();

    // ---- atten[i,l] = feats_i . lang[bi,l] : one (p,l) per thread ----
    int pp = t >> 4, l = t & 15;
    int bi = i0 >> 10;
    const float4* lr = (const float4*)(lang + (bi * L_TOK + l) * FDIM);
    float acc = 0.f;
#pragma unroll
    for (int k = 0; k < FDIM / 4; k++) {
        float4 x = lr[k];
        float4 y = *(const float4*)&fbuf[pp * FBS + 4 * k];
        acc += x.x * y.x + x.y * y.y + x.z * y.z + x.w * y.w;
    }
    atten[(i0 + pp) * L_TOK + l] = acc;
}

// =====================================================================
// D: edge kernel — one query per wave, zero LDS/barriers.
// Softmax via 16-lane shuffles; ew/ctx via bf16 MFMA 16x16x32 with
// preconverted bf16 B-fragments (wr2t, langT) loaded as short8.
// =====================================================================
__global__ __launch_bounds__(256) void edge_kernel(const float* __restrict__ xyz,
                                                   const float* __restrict__ mask,
                                                   const float* __restrict__ Wr1,
                                                   const float* __restrict__ br1,
                                                   const short* __restrict__ wr2t,
                                                   const float* __restrict__ br2,
                                                   const int* __restrict__ knn,
                                                   const short* __restrict__ langT,
                                                   const float* __restrict__ feats,
                                                   const float* __restrict__ atten,
                                                   float* __restrict__ out) {
    int lane = threadIdx.x & 63;
    int wid  = threadIdx.x >> 6;
    int i    = blockIdx.x * 4 + wid;          // query
    int bi   = i >> 10;
    int quad = lane >> 4;
    int e16  = lane & 15;

    int idxe = knn[i * KNN + e16];

    // ---- gather logits: lane holds l = quad*8 + j (quads 0,1 real) ----
    float sat[8];
    if (quad < 2) {
        const float4* ap = (const float4*)(atten + idxe * L_TOK + quad * 8);
        float4 a0 = ap[0], a1 = ap[1];
        sat[0] = a0.x; sat[1] = a0.y; sat[2] = a0.z; sat[3] = a0.w;
        sat[4] = a1.x; sat[5] = a1.y; sat[6] = a1.z; sat[7] = a1.w;
    } else {
#pragma unroll
        for (int j = 0; j < 8; j++) sat[j] = 0.f;
    }

    // ---- segment softmax over e (16-lane shuffle groups) ----
    float mx[8];
#pragma unroll
    for (int j = 0; j < 8; j++) mx[j] = sat[j];
#pragma unroll
    for (int off = 1; off < 16; off <<= 1) {
#pragma unroll
        for (int j = 0; j < 8; j++) mx[j] = fmaxf(mx[j], __shfl_xor(mx[j], off, 16));
    }
    float ex[8], sm[8];
#pragma unroll
    for (int j = 0; j < 8; j++) { ex[j] = __expf(sat[j] - mx[j]); sm[j] = ex[j]; }
#pragma unroll
    for (int off = 1; off < 16; off <<= 1) {
#pragma unroll
        for (int j = 0; j < 8; j++) sm[j] += __shfl_xor(sm[j], off, 16);
    }
    float st[8];
    if (quad < 2) {
        const float4* mp = (const float4*)(mask + i * L_TOK + quad * 8);
        float4 m0 = mp[0], m1 = mp[1];
        float mv[8] = {m0.x, m0.y, m0.z, m0.w, m1.x, m1.y, m1.z, m1.w};
#pragma unroll
        for (int j = 0; j < 8; j++) st[j] = ex[j] * (mv[j] / sm[j]);
    } else {
#pragma unroll
        for (int j = 0; j < 8; j++) st[j] = 0.f;
    }
    float s = st[0] + st[1] + st[2] + st[3] + st[4] + st[5] + st[6] + st[7];
    s += __shfl_xor(s, 16, 64);
    s += __shfl_xor(s, 32, 64);
    float inv2 = 1.f / (s + 1e-7f);
    short8 sattA;
#pragma unroll
    for (int j = 0; j < 8; j++) sattA[j] = f2bf(st[j] * inv2);

    // ---- rel_encoder hidden: hid[e=lane&15][k = s*32+quad*8+j] ----
    float xi0 = xyz[i * 3 + 0], xi1 = xyz[i * 3 + 1], xi2 = xyz[i * 3 + 2];
    float xj0 = xyz[idxe * 3 + 0], xj1 = xyz[idxe * 3 + 1], xj2 = xyz[idxe * 3 + 2];
    float d0 = xi0 - xj0, d1 = xi1 - xj1, d2v = xi2 - xj2;
    float nr = sqrtf(d0 * d0 + d1 * d1 + d2v * d2v + 1e-12f);
    float ein[10] = {xi0, xi1, xi2, xj0, xj1, xj2, d0, d1, d2v, nr};
    short8 hidA[2];
#pragma unroll
    for (int sstep = 0; sstep < 2; sstep++) {
        int k0 = sstep * 32 + quad * 8;
        float h[8];
        const float4* bp = (const float4*)(br1 + k0);
        float4 b0 = bp[0], b1v = bp[1];
        h[0] = b0.x; h[1] = b0.y; h[2] = b0.z; h[3] = b0.w;
        h[4] = b1v.x; h[5] = b1v.y; h[6] = b1v.z; h[7] = b1v.w;
#pragma unroll
        for (int m = 0; m < 10; m++) {
            const float4* wp = (const float4*)(Wr1 + m * RH + k0);
            float4 w0 = wp[0], w1 = wp[1];
            float em = ein[m];
            h[0] += em * w0.x; h[1] += em * w0.y; h[2] += em * w0.z; h[3] += em * w0.w;
            h[4] += em * w1.x; h[5] += em * w1.y; h[6] += em * w1.z; h[7] += em * w1.w;
        }
#pragma unroll
        for (int j = 0; j < 8; j++) hidA[sstep][j] = f2bf(fmaxf(h[j], 0.f));
    }

    int idxr[4];
#pragma unroll
    for (int r = 0; r < 4; r++) idxr[r] = knn[i * KNN + quad * 4 + r];

    // ---- per c-tile: ew MFMA (2 steps) + ctx MFMA (1 padded step) ----
#pragma unroll 2
    for (int tile = 0; tile < 8; tile++) {
        int cc = tile * 16 + e16;
        const short8* w2p = (const short8*)(wr2t + cc * RH);
        f32x4 accew = {0.f, 0.f, 0.f, 0.f};
        accew = __builtin_amdgcn_mfma_f32_16x16x32_bf16(hidA[0], w2p[quad],     accew, 0, 0, 0);
        accew = __builtin_amdgcn_mfma_f32_16x16x32_bf16(hidA[1], w2p[4 + quad], accew, 0, 0, 0);
        short8 lsB;
        if (quad < 2) {
            lsB = ((const short8*)(langT + (bi * FDIM + cc) * L_TOK))[quad];
        } else {
#pragma unroll
            for (int j = 0; j < 8; j++) lsB[j] = 0;
        }
        f32x4 accctx = {0.f, 0.f, 0.f, 0.f};
        accctx = __builtin_amdgcn_mfma_f32_16x16x32_bf16(sattA, lsB, accctx, 0, 0, 0);

        float br2c = br2[cc];
        float msum = 0.f;
#pragma unroll
        for (int r = 0; r < 4; r++) {
            float fj = feats[idxr[r] * FDIM + cc];
            msum += fj * accctx[r] * (accew[r] + br2c);
        }
        msum += __shfl_xor(msum, 16, 64);
        msum += __shfl_xor(msum, 32, 64);
        if (lane < 16)
            out[i * FDIM + cc] = feats[i * FDIM + cc] + msum;
    }
}

extern "C" void kernel_launch(void* const* d_in, const int* in_sizes, int n_in,
                              void* d_out, int out_size, void* d_ws, size_t ws_size,
                              hipStream_t stream) {
    const float* xyz   = (const float*)d_in[0];
    // d_in[1] = batch_index (int32) — layout-implied (i>>10), unused
    const float* features = (const float*)d_in[2];
    const float* lang_f   = (const float*)d_in[3];
    const float* mask     = (const float*)d_in[4];
    const float* W1   = (const float*)d_in[5];
    const float* b1   = (const float*)d_in[6];
    const float* ln_g = (const float*)d_in[7];
    const float* ln_b = (const float*)d_in[8];
    const float* W2   = (const float*)d_in[9];
    const float* b2   = (const float*)d_in[10];
    const float* Wl1  = (const float*)d_in[11];
    const float* bl1  = (const float*)d_in[12];
    const float* bn_g = (const float*)d_in[13];
    const float* bn_b = (const float*)d_in[14];
    const float* Wl2  = (const float*)d_in[15];
    const float* bl2  = (const float*)d_in[16];
    const float* Wr1  = (const float*)d_in[17];
    const float* br1  = (const float*)d_in[18];
    const float* Wr2  = (const float*)d_in[19];
    const float* br2  = (const float*)d_in[20];

    float* ws_feats = (float*)d_ws;                       // N*F
    float* ws_atten = ws_feats + N_PTS * FDIM;            // N*L
    float* ws_lang  = ws_atten + N_PTS * L_TOK;           // B*L*F
    float* ws_hl    = ws_lang + B_SZ * L_TOK * FDIM;      // 64*F
    int*   ws_knn   = (int*)(ws_hl + 64 * FDIM);          // N*K ints
    short* ws_wr2t  = (short*)(ws_knn + N_PTS * KNN);     // 128*64 bf16
    short* ws_langT = ws_wr2t + FDIM * RH;                // B*128*16 bf16
    short* ws_w1t_hi = ws_langT + B_SZ * FDIM * L_TOK;    // 128*256
    short* ws_w1t_lo = ws_w1t_hi + FDIM * FV;             // 128*256
    short* ws_w2t_hi = ws_w1t_lo + FDIM * FV;             // 128*128
    short* ws_w2t_lo = ws_w2t_hi + FDIM * FDIM;           // 128*128

    kA_kernel<<<1092, 256, 0, stream>>>(xyz, lang_f, Wl1, bl1, Wr2, W1, W2,
                                        ws_knn, ws_hl, ws_wr2t,
                                        ws_w1t_hi, ws_w1t_lo, ws_w2t_hi, ws_w2t_lo);
    lang2_kernel<<<16, 128, 0, stream>>>(ws_hl, bn_g, bn_b, Wl2, bl2,
                                         ws_lang, ws_langT);
    feat_kernel<<<N_PTS / 16, 256, 0, stream>>>(features, b1, ln_g, ln_b, b2,
                                                ws_w1t_hi, ws_w1t_lo,
                                                ws_w2t_hi, ws_w2t_lo,
                                                ws_lang, ws_feats, ws_atten);
    edge_kernel<<<N_PTS / 4, 256, 0, stream>>>(xyz, mask, Wr1, br1, ws_wr2t, br2,
                                               ws_knn, ws_langT, ws_feats, ws_atten,
                                               (float*)d_out);
}

// Round 8
// 170.472 us; speedup vs baseline: 1.0217x; 1.0045x over previous
//
#include <hip/hip_runtime.h>

typedef unsigned long long u64;
typedef short short8 __attribute__((ext_vector_type(8)));
typedef short short4v __attribute__((ext_vector_type(4)));
typedef float f32x4 __attribute__((ext_vector_type(4)));

#define N_PTS   4096
#define B_SZ    4
#define N_PER_B 1024
#define L_TOK   16
#define FV      256
#define FL      768
#define FDIM    128
#define KNN     16
#define RH      64   // rel_encoder hidden

#define FINS 264   // fin LDS row stride (shorts), 528B = 16B-aligned
#define RBS  136   // rbuf LDS row stride (shorts), 272B
#define FBS  132   // fbuf LDS row stride (floats), 528B

__device__ __forceinline__ short f2bf(float f) {
    unsigned int x = __float_as_uint(f);
    unsigned int r = (x + 0x7fffu + ((x >> 16) & 1u)) >> 16;
    return (short)r;
}
__device__ __forceinline__ float bf2f(short s) {
    return __uint_as_float(((unsigned int)(unsigned short)s) << 16);
}
__device__ __forceinline__ int mbcnt64(u64 m) {
    return __builtin_amdgcn_mbcnt_hi((unsigned)(m >> 32),
                                     __builtin_amdgcn_mbcnt_lo((unsigned)m, 0));
}

// =====================================================================
// A: knn (1024) + lang1 (64) + weight->bf16 hi/lo transposes (4 blocks)
// kNN radix-select; xk[] eliminated (xk == keys ^ prefix invariant) and
// launch_bounds(256,2) so keys[16] stays in registers — the round-7
// version spilled 32 VGPRs of arrays to scratch (VGPR_Count=40).
// =====================================================================
__global__ __launch_bounds__(256, 2) void kA_kernel(const float* __restrict__ xyz,
                                                 const float* __restrict__ lf,
                                                 const float* __restrict__ Wl1,
                                                 const float* __restrict__ bl1,
                                                 const float* __restrict__ Wr2,
                                                 const float* __restrict__ W1,
                                                 const float* __restrict__ W2,
                                                 int* __restrict__ knn,
                                                 float* __restrict__ hl,
                                                 short* __restrict__ wr2t,
                                                 short* __restrict__ w1t_hi,
                                                 short* __restrict__ w1t_lo,
                                                 short* __restrict__ w2t_hi,
                                                 short* __restrict__ w2t_lo) {
    __shared__ float smem[1024];
    int b = blockIdx.x, t = threadIdx.x;

    if (b < 1024) {
        // ---------------- kNN: one wave per query, radix-select -------
        int lane = t & 63;
        int q = b * 4 + (t >> 6);
        int base = (q >> 10) << 10;
        float qx = xyz[q * 3 + 0];
        float qy = xyz[q * 3 + 1];
        float qz = xyz[q * 3 + 2];
        unsigned keys[16];
#pragma unroll
        for (int m = 0; m < 16; m++) {
            int j = base + lane + (m << 6);
            float dx = qx - xyz[j * 3 + 0];
            float dy = qy - xyz[j * 3 + 1];
            float dz = qz - xyz[j * 3 + 2];
            // match reference rounding: no fma contraction, (x+y) then +z
            float d2 = __fadd_rn(__fadd_rn(__fmul_rn(dx, dx), __fmul_rn(dy, dy)),
                                 __fmul_rn(dz, dz));
            keys[m] = __float_as_uint(d2);
        }
        // bit-plane descent. Invariant: the "descended" key is
        // keys[m] ^ prefix (no second array needed). After the loop,
        // prefix = 16th-smallest key value; need = ties to take at ==.
        unsigned prefix = 0;
        int need = 16;
#pragma unroll
        for (int bit = 30; bit >= 0; --bit) {
            unsigned lim = 1u << bit;
            int c = 0;
#pragma unroll
            for (int m = 0; m < 16; m++)
                c += __popcll(__ballot((keys[m] ^ prefix) < lim));
            if (c < need) {
                need -= c;
                prefix |= lim;
            }
        }
        // emit: all keys < prefix, plus `need` ties (== prefix) with
        // smallest index (matches top_k's stable tie-break). Order within
        // the query is irrelevant (segment ops are permutation-invariant).
        int pos = 0;
#pragma unroll
        for (int m = 0; m < 16; m++) {
            bool less = keys[m] < prefix;
            bool eqv  = (keys[m] == prefix);
            u64 em = __ballot(eqv);
            bool take_eq = false;
            if (need > 0) {
                int ec = __popcll(em);
                if (ec <= need) {
                    take_eq = eqv;
                    need -= ec;
                } else {
                    take_eq = eqv && (mbcnt64(em) < need);
                    need = 0;
                }
            }
            bool sel = less || take_eq;
            u64 sm = __ballot(sel);
            if (sel) {
                int my = pos + mbcnt64(sm);
                knn[q * KNN + my] = base + lane + (m << 6);
            }
            pos += __popcll(sm);
        }
    } else if (b < 1088) {
        // ---------------- lang stage 1: hl = lang_row @ Wl1 + bl1 ------
        int r = b - 1024;
        float* lrow = smem;          // [768]
        float* part = smem + 768;    // [2][128]
        for (int k = t; k < FL; k += 256) lrow[k] = lf[r * FL + k];
        __syncthreads();
        int c = t & 127, kh = t >> 7;
        float acc = (kh == 0) ? bl1[c] : 0.f;
        int k0 = kh * 384;
#pragma unroll 8
        for (int k = k0; k < k0 + 384; k++) acc += lrow[k] * Wl1[k * FDIM + c];
        part[kh * FDIM + c] = acc;
        __syncthreads();
        if (kh == 0) hl[r * FDIM + c] = part[c] + part[FDIM + c];
    } else if (b == 1088) {
        // Wr2 [64][128] -> wr2t bf16 [128][64]
        for (int p = t; p < RH * FDIM; p += 256) {
            int c = p >> 6, k = p & 63;
            wr2t[c * RH + k] = f2bf(Wr2[k * FDIM + c]);
        }
    } else if (b == 1089) {
        // W2 [128][128] -> w2t hi/lo [128c][128k]
        for (int p = t; p < FDIM * FDIM; p += 256) {
            int k = p >> 7, c = p & 127;
            float v = W2[p];
            short h = f2bf(v);
            w2t_hi[c * FDIM + k] = h;
            w2t_lo[c * FDIM + k] = f2bf(v - bf2f(h));
        }
    } else {
        // W1 [256][128] -> w1t hi/lo [128c][256k]; two blocks, k-halves
        int kbase = (b - 1090) * 128;
        for (int p = t; p < 128 * FDIM; p += 256) {
            int k = kbase + (p >> 7), c = p & 127;
            float v = W1[k * FDIM + c];
            short h = f2bf(v);
            w1t_hi[c * FV + k] = h;
            w1t_lo[c * FV + k] = f2bf(v - bf2f(h));
        }
    }
}

// =====================================================================
// B: lang stage 2 — BN (batch stats) + ReLU + GEMM2. 16 blocks × 4 rows.
// Emits lang fp32 and langT bf16 [B][128c][16l].
// =====================================================================
__global__ __launch_bounds__(128) void lang2_kernel(const float* __restrict__ hl,
                                                    const float* __restrict__ bn_g,
                                                    const float* __restrict__ bn_b,
                                                    const float* __restrict__ Wl2,
                                                    const float* __restrict__ bl2,
                                                    float* __restrict__ lang,
                                                    short* __restrict__ langT) {
    __shared__ float rl4[4][FDIM];
    int t = threadIdx.x;
    int r0 = blockIdx.x * 4;
    float s = 0.f, s2 = 0.f;
#pragma unroll 8
    for (int r = 0; r < 64; r++) {
        float v = hl[r * FDIM + t];
        s += v; s2 += v * v;
    }
    float mu = s * (1.f / 64.f);
    float var = s2 * (1.f / 64.f) - mu * mu;
    float rs = rsqrtf(var + 1e-5f);
    float g = bn_g[t], bb = bn_b[t];
#pragma unroll
    for (int p = 0; p < 4; p++)
        rl4[p][t] = fmaxf((hl[(r0 + p) * FDIM + t] - mu) * rs * g + bb, 0.f);
    __syncthreads();
    float bv = bl2[t];
    float a[4] = {bv, bv, bv, bv};
#pragma unroll 8
    for (int k = 0; k < FDIM; k++) {
        float w = Wl2[k * FDIM + t];
        a[0] += rl4[0][k] * w;
        a[1] += rl4[1][k] * w;
        a[2] += rl4[2][k] * w;
        a[3] += rl4[3][k] * w;
    }
#pragma unroll
    for (int p = 0; p < 4; p++) {
        int r = r0 + p;
        lang[r * FDIM + t] = a[p];
        langT[((r >> 4) * FDIM + t) * L_TOK + (r & 15)] = f2bf(a[p]);
    }
}

// =====================================================================
// C: feat encoder via bf16-split MFMA (3-mult, fp32-faithful) + atten.
// 256 blocks × 16 points; wave w owns cols [32w,32w+32) (2 n-tiles).
// =====================================================================
__global__ __launch_bounds__(256) void feat_kernel(const float* __restrict__ features,
                                                   const float* __restrict__ b1,
                                                   const float* __restrict__ ln_g,
                                                   const float* __restrict__ ln_b,
                                                   const float* __restrict__ b2,
                                                   const short* __restrict__ w1t_hi,
                                                   const short* __restrict__ w1t_lo,
                                                   const short* __restrict__ w2t_hi,
                                                   const short* __restrict__ w2t_lo,
                                                   const float* __restrict__ lang,
                                                   float* __restrict__ feats,
                                                   float* __restrict__ atten) {
    __shared__ short fin_hi[16 * FINS], fin_lo[16 * FINS];
    __shared__ short rb_hi[16 * RBS], rb_lo[16 * RBS];
    __shared__ float fbuf[16 * FBS];
    __shared__ float red_s[4 * 16], red_q[4 * 16];
    int t = threadIdx.x;
    int w = t >> 6, lane = t & 63, quad = lane >> 4, e16 = lane & 15;
    int i0 = blockIdx.x * 16;

    // ---- stage features -> bf16 hi/lo in LDS ----
    {
        const float4* src = (const float4*)(features + i0 * FV);
#pragma unroll
        for (int v = 0; v < 4; v++) {
            int flat = t + 256 * v;              // float4 index
            float4 x = src[flat];
            int p = flat >> 6, k = (flat & 63) * 4;
            short4v hi, lo;
            hi[0] = f2bf(x.x); lo[0] = f2bf(x.x - bf2f(hi[0]));
            hi[1] = f2bf(x.y); lo[1] = f2bf(x.y - bf2f(hi[1]));
            hi[2] = f2bf(x.z); lo[2] = f2bf(x.z - bf2f(hi[2]));
            hi[3] = f2bf(x.w); lo[3] = f2bf(x.w - bf2f(hi[3]));
            *(short4v*)&fin_hi[p * FINS + k] = hi;
            *(short4v*)&fin_lo[p * FINS + k] = lo;
        }
    }
    __syncthreads();

    int c0 = 32 * w + e16, c1 = c0 + 16;

    // ---- GEMM1: h = fin @ W1 (3-mult split) ----
    f32x4 acc0 = {0.f, 0.f, 0.f, 0.f}, acc1 = {0.f, 0.f, 0.f, 0.f};
#pragma unroll
    for (int s = 0; s < 8; s++) {
        int ko = s * 32 + quad * 8;
        short8 Ah = *(const short8*)&fin_hi[e16 * FINS + ko];
        short8 Al = *(const short8*)&fin_lo[e16 * FINS + ko];
        short8 B0h = *(const short8*)&w1t_hi[c0 * FV + ko];
        short8 B0l = *(const short8*)&w1t_lo[c0 * FV + ko];
        short8 B1h = *(const short8*)&w1t_hi[c1 * FV + ko];
        short8 B1l = *(const short8*)&w1t_lo[c1 * FV + ko];
        acc0 = __builtin_amdgcn_mfma_f32_16x16x32_bf16(Ah, B0h, acc0, 0, 0, 0);
        acc0 = __builtin_amdgcn_mfma_f32_16x16x32_bf16(Ah, B0l, acc0, 0, 0, 0);
        acc0 = __builtin_amdgcn_mfma_f32_16x16x32_bf16(Al, B0h, acc0, 0, 0, 0);
        acc1 = __builtin_amdgcn_mfma_f32_16x16x32_bf16(Ah, B1h, acc1, 0, 0, 0);
        acc1 = __builtin_amdgcn_mfma_f32_16x16x32_bf16(Ah, B1l, acc1, 0, 0, 0);
        acc1 = __builtin_amdgcn_mfma_f32_16x16x32_bf16(Al, B1h, acc1, 0, 0, 0);
    }
    float b1c0 = b1[c0], b1c1 = b1[c1];
    float h0[4], h1[4], sp[4], qp[4];
#pragma unroll
    for (int r = 0; r < 4; r++) {
        h0[r] = acc0[r] + b1c0;
        h1[r] = acc1[r] + b1c1;
        sp[r] = h0[r] + h1[r];
        qp[r] = h0[r] * h0[r] + h1[r] * h1[r];
    }
#pragma unroll
    for (int off = 1; off < 16; off <<= 1) {
#pragma unroll
        for (int r = 0; r < 4; r++) {
            sp[r] += __shfl_xor(sp[r], off, 16);
            qp[r] += __shfl_xor(qp[r], off, 16);
        }
    }
    if (e16 == 0) {
#pragma unroll
        for (int r = 0; r < 4; r++) {
            red_s[w * 16 + quad * 4 + r] = sp[r];
            red_q[w * 16 + quad * 4 + r] = qp[r];
        }
    }
    __syncthreads();
    float g0 = ln_g[c0], g1 = ln_g[c1], be0 = ln_b[c0], be1 = ln_b[c1];
#pragma unroll
    for (int r = 0; r < 4; r++) {
        int p = quad * 4 + r;
        float S = red_s[p] + red_s[16 + p] + red_s[32 + p] + red_s[48 + p];
        float Q = red_q[p] + red_q[16 + p] + red_q[32 + p] + red_q[48 + p];
        float mu = S * (1.f / 128.f);
        float var = Q * (1.f / 128.f) - mu * mu;
        float rs = rsqrtf(var + 1e-5f);
        float r0 = fmaxf((h0[r] - mu) * rs * g0 + be0, 0.f);
        float r1 = fmaxf((h1[r] - mu) * rs * g1 + be1, 0.f);
        short hh;
        hh = f2bf(r0); rb_hi[p * RBS + c0] = hh; rb_lo[p * RBS + c0] = f2bf(r0 - bf2f(hh));
        hh = f2bf(r1); rb_hi[p * RBS + c1] = hh; rb_lo[p * RBS + c1] = f2bf(r1 - bf2f(hh));
    }
    __syncthreads();

    // ---- GEMM2: f = relu_h @ W2 (3-mult split) ----
    f32x4 o0 = {0.f, 0.f, 0.f, 0.f}, o1 = {0.f, 0.f, 0.f, 0.f};
#pragma unroll
    for (int s = 0; s < 4; s++) {
        int ko = s * 32 + quad * 8;
        short8 Ah = *(const short8*)&rb_hi[e16 * RBS + ko];
        short8 Al = *(const short8*)&rb_lo[e16 * RBS + ko];
        short8 B0h = *(const short8*)&w2t_hi[c0 * FDIM + ko];
        short8 B0l = *(const short8*)&w2t_lo[c0 * FDIM + ko];
        short8 B1h = *(const short8*)&w2t_hi[c1 * FDIM + ko];
        short8 B1l = *(const short8*)&w2t_lo[c1 * FDIM + ko];
        o0 = __builtin_amdgcn_mfma_f32_16x16x32_bf16(Ah, B0h, o0, 0, 0, 0);
        o0 = __builtin_amdgcn_mfma_f32_16x16x32_bf16(Ah, B0l, o0, 0, 0, 0);
        o0 = __builtin_amdgcn_mfma_f32_16x16x32_bf16(Al, B0h, o0, 0, 0, 0);
        o1 = __builtin_amdgcn_mfma_f32_16x16x32_bf16(Ah, B1h, o1, 0, 0, 0);
        o1 = __builtin_amdgcn_mfma_f32_16x16x32_bf16(Ah, B1l, o1, 0, 0, 0);
        o1 = __builtin_amdgcn_mfma_f32_16x16x32_bf16(Al, B1h, o1, 0, 0, 0);
    }
    float b20 = b2[c0], b21 = b2[c1];
#pragma unroll
    for (int r = 0; r < 4; r++) {
        int p = quad * 4 + r;
        float f0 = o0[r] + b20, f1 = o1[r] + b21;
        feats[(i0 + p) * FDIM + c0] = f0;
        feats[(i0 + p) * FDIM + c1] = f1;
        fbuf[p * FBS + c0] = f0;
        fbuf[p * FBS + c1] = f1;
    }
    __syncthreads();

    // ---- atten[i,l] = feats_i . lang[bi,l] : one (p,l) per thread ----
    int pp = t >> 4, l = t & 15;
    int bi = i0 >> 10;
    const float4* lr = (const float4*)(lang + (bi * L_TOK + l) * FDIM);
    float acc = 0.f;
#pragma unroll
    for (int k = 0; k < FDIM / 4; k++) {
        float4 x = lr[k];
        float4 y = *(const float4*)&fbuf[pp * FBS + 4 * k];
        acc += x.x * y.x + x.y * y.y + x.z * y.z + x.w * y.w;
    }
    atten[(i0 + pp) * L_TOK + l] = acc;
}

// =====================================================================
// D: edge kernel — one query per wave, zero LDS/barriers.
// Softmax via 16-lane shuffles; ew/ctx via bf16 MFMA 16x16x32 with
// preconverted bf16 B-fragments (wr2t, langT) loaded as short8.
// =====================================================================
__global__ __launch_bounds__(256) void edge_kernel(const float* __restrict__ xyz,
                                                   const float* __restrict__ mask,
                                                   const float* __restrict__ Wr1,
                                                   const float* __restrict__ br1,
                                                   const short* __restrict__ wr2t,
                                                   const float* __restrict__ br2,
                                                   const int* __restrict__ knn,
                                                   const short* __restrict__ langT,
                                                   const float* __restrict__ feats,
                                                   const float* __restrict__ atten,
                                                   float* __restrict__ out) {
    int lane = threadIdx.x & 63;
    int wid  = threadIdx.x >> 6;
    int i    = blockIdx.x * 4 + wid;          // query
    int bi   = i >> 10;
    int quad = lane >> 4;
    int e16  = lane & 15;

    int idxe = knn[i * KNN + e16];

    // ---- gather logits: lane holds l = quad*8 + j (quads 0,1 real) ----
    float sat[8];
    if (quad < 2) {
        const float4* ap = (const float4*)(atten + idxe * L_TOK + quad * 8);
        float4 a0 = ap[0], a1 = ap[1];
        sat[0] = a0.x; sat[1] = a0.y; sat[2] = a0.z; sat[3] = a0.w;
        sat[4] = a1.x; sat[5] = a1.y; sat[6] = a1.z; sat[7] = a1.w;
    } else {
#pragma unroll
        for (int j = 0; j < 8; j++) sat[j] = 0.f;
    }

    // ---- segment softmax over e (16-lane shuffle groups) ----
    float mx[8];
#pragma unroll
    for (int j = 0; j < 8; j++) mx[j] = sat[j];
#pragma unroll
    for (int off = 1; off < 16; off <<= 1) {
#pragma unroll
        for (int j = 0; j < 8; j++) mx[j] = fmaxf(mx[j], __shfl_xor(mx[j], off, 16));
    }
    float ex[8], sm[8];
#pragma unroll
    for (int j = 0; j < 8; j++) { ex[j] = __expf(sat[j] - mx[j]); sm[j] = ex[j]; }
#pragma unroll
    for (int off = 1; off < 16; off <<= 1) {
#pragma unroll
        for (int j = 0; j < 8; j++) sm[j] += __shfl_xor(sm[j], off, 16);
    }
    float st[8];
    if (quad < 2) {
        const float4* mp = (const float4*)(mask + i * L_TOK + quad * 8);
        float4 m0 = mp[0], m1 = mp[1];
        float mv[8] = {m0.x, m0.y, m0.z, m0.w, m1.x, m1.y, m1.z, m1.w};
#pragma unroll
        for (int j = 0; j < 8; j++) st[j] = ex[j] * (mv[j] / sm[j]);
    } else {
#pragma unroll
        for (int j = 0; j < 8; j++) st[j] = 0.f;
    }
    float s = st[0] + st[1] + st[2] + st[3] + st[4] + st[5] + st[6] + st[7];
    s += __shfl_xor(s, 16, 64);
    s += __shfl_xor(s, 32, 64);
    float inv2 = 1.f / (s + 1e-7f);
    short8 sattA;
#pragma unroll
    for (int j = 0; j < 8; j++) sattA[j] = f2bf(st[j] * inv2);

    // ---- rel_encoder hidden: hid[e=lane&15][k = s*32+quad*8+j] ----
    float xi0 = xyz[i * 3 + 0], xi1 = xyz[i * 3 + 1], xi2 = xyz[i * 3 + 2];
    float xj0 = xyz[idxe * 3 + 0], xj1 = xyz[idxe * 3 + 1], xj2 = xyz[idxe * 3 + 2];
    float d0 = xi0 - xj0, d1 = xi1 - xj1, d2v = xi2 - xj2;
    float nr = sqrtf(d0 * d0 + d1 * d1 + d2v * d2v + 1e-12f);
    float ein[10] = {xi0, xi1, xi2, xj0, xj1, xj2, d0, d1, d2v, nr};
    short8 hidA[2];
#pragma unroll
    for (int sstep = 0; sstep < 2; sstep++) {
        int k0 = sstep * 32 + quad * 8;
        float h[8];
        const float4* bp = (const float4*)(br1 + k0);
        float4 b0 = bp[0], b1v = bp[1];
        h[0] = b0.x; h[1] = b0.y; h[2] = b0.z; h[3] = b0.w;
        h[4] = b1v.x; h[5] = b1v.y; h[6] = b1v.z; h[7] = b1v.w;
#pragma unroll
        for (int m = 0; m < 10; m++) {
            const float4* wp = (const float4*)(Wr1 + m * RH + k0);
            float4 w0 = wp[0], w1 = wp[1];
            float em = ein[m];
            h[0] += em * w0.x; h[1] += em * w0.y; h[2] += em * w0.z; h[3] += em * w0.w;
            h[4] += em * w1.x; h[5] += em * w1.y; h[6] += em * w1.z; h[7] += em * w1.w;
        }
#pragma unroll
        for (int j = 0; j < 8; j++) hidA[sstep][j] = f2bf(fmaxf(h[j], 0.f));
    }

    int idxr[4];
#pragma unroll
    for (int r = 0; r < 4; r++) idxr[r] = knn[i * KNN + quad * 4 + r];

    // ---- per c-tile: ew MFMA (2 steps) + ctx MFMA (1 padded step) ----
#pragma unroll 2
    for (int tile = 0; tile < 8; tile++) {
        int cc = tile * 16 + e16;
        const short8* w2p = (const short8*)(wr2t + cc * RH);
        f32x4 accew = {0.f, 0.f, 0.f, 0.f};
        accew = __builtin_amdgcn_mfma_f32_16x16x32_bf16(hidA[0], w2p[quad],     accew, 0, 0, 0);
        accew = __builtin_amdgcn_mfma_f32_16x16x32_bf16(hidA[1], w2p[4 + quad], accew, 0, 0, 0);
        short8 lsB;
        if (quad < 2) {
            lsB = ((const short8*)(langT + (bi * FDIM + cc) * L_TOK))[quad];
        } else {
#pragma unroll
            for (int j = 0; j < 8; j++) lsB[j] = 0;
        }
        f32x4 accctx = {0.f, 0.f, 0.f, 0.f};
        accctx = __builtin_amdgcn_mfma_f32_16x16x32_bf16(sattA, lsB, accctx, 0, 0, 0);

        float br2c = br2[cc];
        float msum = 0.f;
#pragma unroll
        for (int r = 0; r < 4; r++) {
            float fj = feats[idxr[r] * FDIM + cc];
            msum += fj * accctx[r] * (accew[r] + br2c);
        }
        msum += __shfl_xor(msum, 16, 64);
        msum += __shfl_xor(msum, 32, 64);
        if (lane < 16)
            out[i * FDIM + cc] = feats[i * FDIM + cc] + msum;
    }
}

extern "C" void kernel_launch(void* const* d_in, const int* in_sizes, int n_in,
                              void* d_out, int out_size, void* d_ws, size_t ws_size,
                              hipStream_t stream) {
    const float* xyz   = (const float*)d_in[0];
    // d_in[1] = batch_index (int32) — layout-implied (i>>10), unused
    const float* features = (const float*)d_in[2];
    const float* lang_f   = (const float*)d_in[3];
    const float* mask     = (const float*)d_in[4];
    const float* W1   = (const float*)d_in[5];
    const float* b1   = (const float*)d_in[6];
    const float* ln_g = (const float*)d_in[7];
    const float* ln_b = (const float*)d_in[8];
    const float* W2   = (const float*)d_in[9];
    const float* b2   = (const float*)d_in[10];
    const float* Wl1  = (const float*)d_in[11];
    const float* bl1  = (const float*)d_in[12];
    const float* bn_g = (const float*)d_in[13];
    const float* bn_b = (const float*)d_in[14];
    const float* Wl2  = (const float*)d_in[15];
    const float* bl2  = (const float*)d_in[16];
    const float* Wr1  = (const float*)d_in[17];
    const float* br1  = (const float*)d_in[18];
    const float* Wr2  = (const float*)d_in[19];
    const float* br2  = (const float*)d_in[20];

    float* ws_feats = (float*)d_ws;                       // N*F
    float* ws_atten = ws_feats + N_PTS * FDIM;            // N*L
    float* ws_lang  = ws_atten + N_PTS * L_TOK;           // B*L*F
    float* ws_hl    = ws_lang + B_SZ * L_TOK * FDIM;      // 64*F
    int*   ws_knn   = (int*)(ws_hl + 64 * FDIM);          // N*K ints
    short* ws_wr2t  = (short*)(ws_knn + N_PTS * KNN);     // 128*64 bf16
    short* ws_langT = ws_wr2t + FDIM * RH;                // B*128*16 bf16
    short* ws_w1t_hi = ws_langT + B_SZ * FDIM * L_TOK;    // 128*256
    short* ws_w1t_lo = ws_w1t_hi + FDIM * FV;             // 128*256
    short* ws_w2t_hi = ws_w1t_lo + FDIM * FV;             // 128*128
    short* ws_w2t_lo = ws_w2t_hi + FDIM * FDIM;           // 128*128

    kA_kernel<<<1092, 256, 0, stream>>>(xyz, lang_f, Wl1, bl1, Wr2, W1, W2,
                                        ws_knn, ws_hl, ws_wr2t,
                                        ws_w1t_hi, ws_w1t_lo, ws_w2t_hi, ws_w2t_lo);
    lang2_kernel<<<16, 128, 0, stream>>>(ws_hl, bn_g, bn_b, Wl2, bl2,
                                         ws_lang, ws_langT);
    feat_kernel<<<N_PTS / 16, 256, 0, stream>>>(features, b1, ln_g, ln_b, b2,
                                                ws_w1t_hi, ws_w1t_lo,
                                                ws_w2t_hi, ws_w2t_lo,
                                                ws_lang, ws_feats, ws_atten);
    edge_kernel<<<N_PTS / 4, 256, 0, stream>>>(xyz, mask, Wr1, br1, ws_wr2t, br2,
                                               ws_knn, ws_langT, ws_feats, ws_atten,
                                               (float*)d_out);
}